// Round 1
// baseline (576.163 us; speedup 1.0000x reference)
//
#include <hip/hip_runtime.h>
#include <hip/hip_bf16.h>
#include <stdint.h>

typedef float  f32x4  __attribute__((ext_vector_type(4)));
typedef short  bf16x8 __attribute__((ext_vector_type(8)));
typedef unsigned short u16x8 __attribute__((ext_vector_type(8)));

#define MFMA16(a, b, c) __builtin_amdgcn_mfma_f32_16x16x32_bf16((a), (b), (c), 0, 0, 0)

__device__ __forceinline__ void gload16(const void* g, void* l) {
  __builtin_amdgcn_global_load_lds((const __attribute__((address_space(1))) void*)g,
                                   (__attribute__((address_space(3))) void*)l,
                                   16, 0, 0);
}

__device__ __forceinline__ unsigned short bf16bits(float f) {
  __hip_bfloat16 h = __float2bfloat16(f);
  return *(unsigned short*)&h;
}

__device__ __forceinline__ float bf2f(unsigned short u) {
  unsigned int x = ((unsigned int)u) << 16;
  return *(float*)&x;
}

// LDS-only barrier: waits DS ops, leaves global loads (register targets) in
// flight across the barrier. Memory clobbers pin compiler-generated LDS ops
// to their side; s_barrier itself is the wave sync.
__device__ __forceinline__ void block_sync_lds() {
  asm volatile("s_waitcnt lgkmcnt(0)" ::: "memory");
  __builtin_amdgcn_s_barrier();
  asm volatile("" ::: "memory");
}

// ---------------- fp32 -> bf16 cast, 4 elems/thread ----------------
__global__ void cast_kernel(const float* __restrict__ s, __hip_bfloat16* __restrict__ d, int n4) {
  int i = blockIdx.x * blockDim.x + threadIdx.x;
  if (i < n4) {
    float4 v = ((const float4*)s)[i];
    ushort4 u;
    u.x = bf16bits(v.x); u.y = bf16bits(v.y); u.z = bf16bits(v.z); u.w = bf16bits(v.w);
    ((ushort4*)d)[i] = u;
  }
}

// ---------------- GEMM1: qkv = xb @ wqkvb^T + b_qkv; scatter to Q,K,Vt (bf16) ----------------
__global__ __launch_bounds__(256) void gemm_qkv_kernel(
    const __hip_bfloat16* __restrict__ A,
    const __hip_bfloat16* __restrict__ B,
    const float* __restrict__ bias,
    __hip_bfloat16* __restrict__ Qo,
    __hip_bfloat16* __restrict__ Ko,
    __hip_bfloat16* __restrict__ Vt) {
  const int K = 1024;
  __shared__ __align__(16) __hip_bfloat16 As[128 * 32];
  __shared__ __align__(16) __hip_bfloat16 Bs[128 * 32];
  const int t = threadIdx.x;
  const int lane = t & 63, wv = t >> 6;
  const int wm = (wv >> 1) * 64, wn = (wv & 1) * 64;
  const int lr = lane & 15, lq = lane >> 4;
  const int m0 = blockIdx.y * 128, n0 = blockIdx.x * 128;

  f32x4 acc[4][4] = {};

  const int arow = t >> 2;
  const int acol = (t & 3) * 8;
  const __hip_bfloat16* Ag = A + (long)(m0 + arow) * K + acol;
  const __hip_bfloat16* Bg = B + (long)(n0 + arow) * K + acol;
  __hip_bfloat16* Asl = As + t * 8;
  __hip_bfloat16* Bsl = Bs + t * 8;

  for (int kk = 0; kk < K; kk += 32) {
    gload16(Ag + kk, Asl);
    gload16(Ag + kk + 64 * K, Asl + 2048);
    gload16(Bg + kk, Bsl);
    gload16(Bg + kk + 64 * K, Bsl + 2048);
    __syncthreads();
    bf16x8 af[4], bf[4];
#pragma unroll
    for (int i = 0; i < 4; ++i)
      af[i] = *(const bf16x8*)&As[(wm + i * 16 + lr) * 32 + lq * 8];
#pragma unroll
    for (int j = 0; j < 4; ++j)
      bf[j] = *(const bf16x8*)&Bs[(wn + j * 16 + lr) * 32 + lq * 8];
#pragma unroll
    for (int i = 0; i < 4; ++i)
#pragma unroll
      for (int j = 0; j < 4; ++j)
        acc[i][j] = MFMA16(af[i], bf[j], acc[i][j]);
    __syncthreads();
  }

#pragma unroll
  for (int i = 0; i < 4; ++i) {
#pragma unroll
    for (int j = 0; j < 4; ++j) {
      int col = n0 + wn + j * 16 + lr;
      int tsel = col >> 10, rem = col & 1023;
      int h = rem >> 6, d = rem & 63;
      float bs = bias[col];
      int rowb = m0 + wm + i * 16 + lq * 4;
#pragma unroll
      for (int r = 0; r < 4; ++r) {
        int m = rowb + r;
        int b = m >> 11, sdx = m & 2047;
        __hip_bfloat16 v = __float2bfloat16(acc[i][j][r] + bs);
        long bh = (long)(b * 16 + h);
        if (tsel == 0)       Qo[(bh * 2048 + sdx) * 64 + d] = v;
        else if (tsel == 1)  Ko[(bh * 2048 + sdx) * 64 + d] = v;
        else                 Vt[(bh * 64 + d) * 2048 + sdx] = v;
      }
    }
  }
}

// ---------------- fused attention, QBLK=32, 512 threads ----------------
// Grid 512; combo = blockIdx&7 -> (b,chunk) keeps one K/V working set per XCD.
// 8 waves: QK^T split as (k-quarter kh = wv&3) x (head-group hg = wv>>2, 8 heads),
// so K is loaded ONCE per block-iter (was twice the traffic per q-row at QBLK=16).
// Head-axis softmax: each wave holds 8 of 16 head exponentials per (q,k) cell;
// the two hg waves exchange partial sums through psum[2][32][66] (pad 66 ->
// conflict-free f32 pattern). PV: wave owns 2 heads x all 32 q, V loaded once.
// Raw s_barrier + lgkmcnt-only waits allow V loads (issued after QK) and the
// next K tile (issued after the P-write) to stay in flight across barriers.
// LDS 145 KB -> 1 block/CU (8 waves). Granule-XOR swizzle as before.
__global__ __launch_bounds__(512, 2) void attn_kernel(
    const __hip_bfloat16* __restrict__ Q,
    const __hip_bfloat16* __restrict__ K,
    const __hip_bfloat16* __restrict__ Vt,
    __hip_bfloat16* __restrict__ part) {
  __shared__ __align__(16) __hip_bfloat16 Qs[512 * 64];  // 64 KB  rows = h*32+q
  __shared__ __align__(16) __hip_bfloat16 P[512 * 64];   // 64 KB  rows = h*32+q
  __shared__ float psum[2][32][66];                      // 16.5 KB, pad 66
  const int t = threadIdx.x, lane = t & 63, wv = t >> 6;
  const int lr = lane & 15, lq = lane >> 4;
  const int kh = wv & 3, hg = wv >> 2;
  const int combo = blockIdx.x & 7;
  const int b = combo & 1, chunk = combo >> 1;
  const int q0 = (blockIdx.x >> 3) * 32;
  const int k0 = chunk * 512;
  const float c = 0.03125f * 1.44269504f;  // (1/sqrt(E)) * log2(e), E=1024
  const long bh16 = (long)(b * 16);

  // ---- stage Q tile: 512 rows (h = t>>5, q = t&31), granule-XOR swizzle ----
  {
    const int row = t;
    const __hip_bfloat16* gq = Q + ((bh16 + (t >> 5)) * 2048 + q0 + (t & 31)) * 64;
#pragma unroll
    for (int j = 0; j < 8; ++j) {
      bf16x8 v = *(const bf16x8*)(gq + j * 8);
      *(bf16x8*)&Qs[row * 64 + ((j ^ (row & 7)) << 3)] = v;
    }
  }

  f32x4 ctx[2][2][4] = {};

  // K: wave reads k-rows kh*16+lr for heads hg*8..hg*8+7, d cols lq*8 / +32
  const __hip_bfloat16* kb =
      K + ((bh16 + hg * 8) * 2048 + k0 + kh * 16 + lr) * 64 + lq * 8;
  // V: wave's PV heads wv*2, wv*2+1; d-rows dt*16+lr, k cols kk+lq*8 / +32
  const __hip_bfloat16* vb =
      Vt + ((bh16 + wv * 2) * 64 + lr) * 2048 + k0 + lq * 8;

  // prologue: first K tile issued before the Qs barrier (stays in flight)
  bf16x8 kf[16];
#pragma unroll
  for (int h = 0; h < 8; ++h) {
    const __hip_bfloat16* kp = kb + (long)h * (2048 * 64);
    kf[2 * h]     = *(const bf16x8*)kp;
    kf[2 * h + 1] = *(const bf16x8*)(kp + 32);
  }
  block_sync_lds();

  for (int kk = k0; kk < k0 + 512; kk += 64) {
    // ---- QK^T: 8 heads x 2 q-halves, K dim 64 via chained pair ----
    f32x4 s[8][2];
    __builtin_amdgcn_s_setprio(1);
#pragma unroll
    for (int h = 0; h < 8; ++h) {
      const int hrow = (hg * 8 + h) * 32;
#pragma unroll
      for (int qh = 0; qh < 2; ++qh) {
        const int qrow = hrow + qh * 16 + lr;
        bf16x8 qa = *(const bf16x8*)&Qs[qrow * 64 + ((lq ^ (lr & 7)) << 3)];
        bf16x8 qb = *(const bf16x8*)&Qs[qrow * 64 + (((lq + 4) ^ (lr & 7)) << 3)];
        f32x4 a = {};
        a = MFMA16(qa, kf[2 * h], a);
        a = MFMA16(qb, kf[2 * h + 1], a);
        s[h][qh] = a;
      }
    }
    __builtin_amdgcn_s_setprio(0);
    // ---- V loads for this kk: latency hidden under softmax + barriers ----
    bf16x8 vf[16];
#pragma unroll
    for (int hh = 0; hh < 2; ++hh) {
      const __hip_bfloat16* vbh = vb + (long)hh * (64 * 2048) + (kk - k0);
#pragma unroll
      for (int dt = 0; dt < 4; ++dt) {
        vf[hh * 8 + dt * 2]     = *(const bf16x8*)(vbh + (long)dt * 16 * 2048);
        vf[hh * 8 + dt * 2 + 1] = *(const bf16x8*)(vbh + (long)dt * 16 * 2048 + 32);
      }
    }
    // ---- exp + this wave's 8-head partial sums (no max-sub: |s*c| small) ----
    f32x4 ps[2] = {};
#pragma unroll
    for (int h = 0; h < 8; ++h)
#pragma unroll
      for (int qh = 0; qh < 2; ++qh) {
#pragma unroll
        for (int r = 0; r < 4; ++r) s[h][qh][r] = __builtin_amdgcn_exp2f(s[h][qh][r] * c);
        ps[qh] += s[h][qh];
      }
    {
      const int kcol = kh * 16 + lr;
#pragma unroll
      for (int qh = 0; qh < 2; ++qh)
#pragma unroll
        for (int r = 0; r < 4; ++r)
          psum[hg][qh * 16 + lq * 4 + r][kcol] = ps[qh][r];
    }
    block_sync_lds();
    // ---- total = own + partner-hg partial; normalize; write P ----
    f32x4 inv[2];
    {
      const int kcol = kh * 16 + lr;
#pragma unroll
      for (int qh = 0; qh < 2; ++qh)
#pragma unroll
        for (int r = 0; r < 4; ++r)
          inv[qh][r] = __builtin_amdgcn_rcpf(
              ps[qh][r] + psum[1 - hg][qh * 16 + lq * 4 + r][kcol]);
    }
    {
      const int gcol = (kh * 16 + lr) >> 3, coff = lr & 7;
#pragma unroll
      for (int h = 0; h < 8; ++h) {
        const int hrow = (hg * 8 + h) * 32;
#pragma unroll
        for (int qh = 0; qh < 2; ++qh)
#pragma unroll
          for (int r = 0; r < 4; ++r) {
            int row = hrow + qh * 16 + lq * 4 + r;
            P[row * 64 + ((gcol ^ (row & 7)) << 3) + coff] =
                __float2bfloat16(s[h][qh][r] * inv[qh][r]);
          }
      }
    }
    // ---- prefetch next K tile; rides in flight across the PV phase ----
    if (kk + 64 < k0 + 512) {
#pragma unroll
      for (int h = 0; h < 8; ++h) {
        const __hip_bfloat16* kp = kb + (long)h * (2048 * 64) + (long)(kk + 64 - k0) * 64;
        kf[2 * h]     = *(const bf16x8*)kp;
        kf[2 * h + 1] = *(const bf16x8*)(kp + 32);
      }
    }
    block_sync_lds();
    // ---- PV: 2 heads x 2 q-halves x 4 d-tiles ----
    __builtin_amdgcn_s_setprio(1);
#pragma unroll
    for (int hh = 0; hh < 2; ++hh) {
      const int h = wv * 2 + hh;
#pragma unroll
      for (int qh = 0; qh < 2; ++qh) {
        const int prow = h * 32 + qh * 16 + lr;
        bf16x8 pf0 = *(const bf16x8*)&P[prow * 64 + ((lq ^ (lr & 7)) << 3)];
        bf16x8 pf1 = *(const bf16x8*)&P[prow * 64 + (((lq + 4) ^ (lr & 7)) << 3)];
#pragma unroll
        for (int dt = 0; dt < 4; ++dt) {
          ctx[hh][qh][dt] = MFMA16(pf0, vf[hh * 8 + dt * 2], ctx[hh][qh][dt]);
          ctx[hh][qh][dt] = MFMA16(pf1, vf[hh * 8 + dt * 2 + 1], ctx[hh][qh][dt]);
        }
      }
    }
    __builtin_amdgcn_s_setprio(0);
    block_sync_lds();
  }

  // ---- epilogue: ctx -> LDS (reuse P, same swizzle) -> coalesced wide store ----
  unsigned short* Pc = (unsigned short*)P;
#pragma unroll
  for (int hh = 0; hh < 2; ++hh) {
    const int h = wv * 2 + hh;
#pragma unroll
    for (int qh = 0; qh < 2; ++qh)
#pragma unroll
      for (int dt = 0; dt < 4; ++dt) {
        int g = dt * 2 + (lr >> 3), off = lr & 7;
#pragma unroll
        for (int r = 0; r < 4; ++r) {
          int row = h * 32 + qh * 16 + lq * 4 + r;
          Pc[row * 64 + ((g ^ (row & 7)) << 3) + off] = bf16bits(ctx[hh][qh][dt][r]);
        }
      }
  }
  block_sync_lds();
  // part[chunk][b][q0..q0+31][h*64+d]: contiguous 64 KB per CTA.
  unsigned short* gbase = (unsigned short*)part + ((long)(chunk * 4096 + b * 2048 + q0)) * 1024;
#pragma unroll
  for (int j = 0; j < 8; ++j) {
    int gf = (j * 512 + t) * 8;            // flat over [32q][16h][64d]
    int q = gf >> 10, hd = gf & 1023;
    int h = hd >> 6, d = hd & 63;
    int row = h * 32 + q, gd = (d >> 3) & 7;
    u16x8 v = *(const u16x8*)&Pc[row * 64 + ((gd ^ (row & 7)) << 3)];
    *(u16x8*)&gbase[gf] = v;
  }
}

// ---------------- reduce 4 bf16 chunk partials + cast to bf16 ----------------
__global__ void reduce_cast_kernel(const unsigned short* __restrict__ part,
                                   __hip_bfloat16* __restrict__ dst) {
  int i = blockIdx.x * blockDim.x + threadIdx.x;  // 1M threads, 4 elems each
  const long S4 = (long)4096 * 1024 / 4;          // ushort4 units per chunk
  const ushort4* p = (const ushort4*)part;
  float sx = 0.f, sy = 0.f, sz = 0.f, sw = 0.f;
#pragma unroll
  for (int c = 0; c < 4; ++c) {
    ushort4 v = p[i + c * S4];
    sx += bf2f(v.x); sy += bf2f(v.y); sz += bf2f(v.z); sw += bf2f(v.w);
  }
  ushort4 u;
  u.x = bf16bits(sx); u.y = bf16bits(sy); u.z = bf16bits(sz); u.w = bf16bits(sw);
  ((ushort4*)dst)[i] = u;
}

// ---------------- GEMM2: out = ctxb @ woutb^T + b_out (fp32 out) ----------------
__global__ __launch_bounds__(256) void gemm_out_kernel(
    const __hip_bfloat16* __restrict__ A,   // [4096][1024]
    const __hip_bfloat16* __restrict__ B,   // [1024][1024]
    const float* __restrict__ bias,
    float* __restrict__ out) {
  const int K = 1024;
  __shared__ __align__(16) __hip_bfloat16 As[128 * 32];
  __shared__ __align__(16) __hip_bfloat16 Bs[128 * 32];
  const int t = threadIdx.x;
  const int lane = t & 63, wv = t >> 6;
  const int wm = (wv >> 1) * 64, wn = (wv & 1) * 64;
  const int lr = lane & 15, lq = lane >> 4;
  const int m0 = blockIdx.y * 128, n0 = blockIdx.x * 128;

  f32x4 acc[4][4] = {};

  const int arow = t >> 2;
  const int acol = (t & 3) * 8;
  const __hip_bfloat16* Ag = A + (long)(m0 + arow) * K + acol;
  const __hip_bfloat16* Bg = B + (long)(n0 + arow) * K + acol;
  __hip_bfloat16* Asl = As + t * 8;
  __hip_bfloat16* Bsl = Bs + t * 8;

  for (int kk = 0; kk < K; kk += 32) {
    gload16(Ag + kk, Asl);
    gload16(Ag + kk + 64 * K, Asl + 2048);
    gload16(Bg + kk, Bsl);
    gload16(Bg + kk + 64 * K, Bsl + 2048);
    __syncthreads();
    bf16x8 af[4], bf[4];
#pragma unroll
    for (int i = 0; i < 4; ++i)
      af[i] = *(const bf16x8*)&As[(wm + i * 16 + lr) * 32 + lq * 8];
#pragma unroll
    for (int j = 0; j < 4; ++j)
      bf[j] = *(const bf16x8*)&Bs[(wn + j * 16 + lr) * 32 + lq * 8];
#pragma unroll
    for (int i = 0; i < 4; ++i)
#pragma unroll
      for (int j = 0; j < 4; ++j)
        acc[i][j] = MFMA16(af[i], bf[j], acc[i][j]);
    __syncthreads();
  }

#pragma unroll
  for (int i = 0; i < 4; ++i) {
#pragma unroll
    for (int j = 0; j < 4; ++j) {
      int col = n0 + wn + j * 16 + lr;
      float bs = bias[col];
      int rowb = m0 + wm + i * 16 + lq * 4;
#pragma unroll
      for (int r = 0; r < 4; ++r) {
        out[(long)(rowb + r) * 1024 + col] = acc[i][j][r] + bs;
      }
    }
  }
}

extern "C" void kernel_launch(void* const* d_in, const int* in_sizes, int n_in,
                              void* d_out, int out_size, void* d_ws, size_t ws_size,
                              hipStream_t stream) {
  const float* x     = (const float*)d_in[0];
  const float* w_qkv = (const float*)d_in[1];
  const float* b_qkv = (const float*)d_in[2];
  const float* w_out = (const float*)d_in[3];
  const float* b_out = (const float*)d_in[4];
  float* out = (float*)d_out;
  char* ws = (char*)d_ws;

  // workspace layout (80 MB total)
  __hip_bfloat16* xb    = (__hip_bfloat16*)(ws);                       // 8 MB
  __hip_bfloat16* wqkvb = (__hip_bfloat16*)(ws + (8ul << 20));         // 6 MB
  __hip_bfloat16* woutb = (__hip_bfloat16*)(ws + (14ul << 20));        // 2 MB
  __hip_bfloat16* Qb    = (__hip_bfloat16*)(ws + (16ul << 20));        // 8 MB
  __hip_bfloat16* Kb    = (__hip_bfloat16*)(ws + (24ul << 20));        // 8 MB
  __hip_bfloat16* Vtb   = (__hip_bfloat16*)(ws + (32ul << 20));        // 8 MB
  __hip_bfloat16* partb = (__hip_bfloat16*)(ws + (40ul << 20));        // 32 MB (4 bf16 chunks)
  __hip_bfloat16* ctxb  = (__hip_bfloat16*)(ws + (72ul << 20));        // 8 MB

  cast_kernel<<<4096, 256, 0, stream>>>(x, xb, 4194304 / 4);
  cast_kernel<<<3072, 256, 0, stream>>>(w_qkv, wqkvb, 3145728 / 4);
  cast_kernel<<<1024, 256, 0, stream>>>(w_out, woutb, 1048576 / 4);
  gemm_qkv_kernel<<<dim3(24, 32), 256, 0, stream>>>(xb, wqkvb, b_qkv, Qb, Kb, Vtb);
  attn_kernel<<<512, 512, 0, stream>>>(Qb, Kb, Vtb, partb);
  reduce_cast_kernel<<<4096, 256, 0, stream>>>((const unsigned short*)partb, ctxb);
  gemm_out_kernel<<<dim3(8, 32), 256, 0, stream>>>(ctxb, woutb, b_out, out);
}

// Round 3
// 413.716 us; speedup vs baseline: 1.3927x; 1.3927x over previous
//
#include <hip/hip_runtime.h>
#include <hip/hip_bf16.h>
#include <stdint.h>

typedef float  f32x4  __attribute__((ext_vector_type(4)));
typedef short  bf16x8 __attribute__((ext_vector_type(8)));
typedef unsigned short u16x8 __attribute__((ext_vector_type(8)));

#define MFMA16(a, b, c) __builtin_amdgcn_mfma_f32_16x16x32_bf16((a), (b), (c), 0, 0, 0)

__device__ __forceinline__ void gload16(const void* g, void* l) {
  __builtin_amdgcn_global_load_lds((const __attribute__((address_space(1))) void*)g,
                                   (__attribute__((address_space(3))) void*)l,
                                   16, 0, 0);
}

__device__ __forceinline__ unsigned short bf16bits(float f) {
  __hip_bfloat16 h = __float2bfloat16(f);
  return *(unsigned short*)&h;
}

__device__ __forceinline__ float bf2f(unsigned short u) {
  unsigned int x = ((unsigned int)u) << 16;
  return *(float*)&x;
}

// LDS-only barrier: drains DS ops, leaves register-destined global loads in
// flight across the barrier (s_barrier does not drain vmcnt).
__device__ __forceinline__ void block_sync_lds() {
  asm volatile("s_waitcnt lgkmcnt(0)" ::: "memory");
  __builtin_amdgcn_s_barrier();
  asm volatile("" ::: "memory");
}

// ---------------- fp32 -> bf16 cast, 4 elems/thread ----------------
__global__ void cast_kernel(const float* __restrict__ s, __hip_bfloat16* __restrict__ d, int n4) {
  int i = blockIdx.x * blockDim.x + threadIdx.x;
  if (i < n4) {
    float4 v = ((const float4*)s)[i];
    ushort4 u;
    u.x = bf16bits(v.x); u.y = bf16bits(v.y); u.z = bf16bits(v.z); u.w = bf16bits(v.w);
    ((ushort4*)d)[i] = u;
  }
}

// ---------------- GEMM1: qkv = xb @ wqkvb^T + b_qkv; scatter to Q,K,Vt (bf16) ----------------
__global__ __launch_bounds__(256) void gemm_qkv_kernel(
    const __hip_bfloat16* __restrict__ A,
    const __hip_bfloat16* __restrict__ B,
    const float* __restrict__ bias,
    __hip_bfloat16* __restrict__ Qo,
    __hip_bfloat16* __restrict__ Ko,
    __hip_bfloat16* __restrict__ Vt) {
  const int K = 1024;
  __shared__ __align__(16) __hip_bfloat16 As[128 * 32];
  __shared__ __align__(16) __hip_bfloat16 Bs[128 * 32];
  const int t = threadIdx.x;
  const int lane = t & 63, wv = t >> 6;
  const int wm = (wv >> 1) * 64, wn = (wv & 1) * 64;
  const int lr = lane & 15, lq = lane >> 4;
  const int m0 = blockIdx.y * 128, n0 = blockIdx.x * 128;

  f32x4 acc[4][4] = {};

  const int arow = t >> 2;
  const int acol = (t & 3) * 8;
  const __hip_bfloat16* Ag = A + (long)(m0 + arow) * K + acol;
  const __hip_bfloat16* Bg = B + (long)(n0 + arow) * K + acol;
  __hip_bfloat16* Asl = As + t * 8;
  __hip_bfloat16* Bsl = Bs + t * 8;

  for (int kk = 0; kk < K; kk += 32) {
    gload16(Ag + kk, Asl);
    gload16(Ag + kk + 64 * K, Asl + 2048);
    gload16(Bg + kk, Bsl);
    gload16(Bg + kk + 64 * K, Bsl + 2048);
    __syncthreads();
    bf16x8 af[4], bf[4];
#pragma unroll
    for (int i = 0; i < 4; ++i)
      af[i] = *(const bf16x8*)&As[(wm + i * 16 + lr) * 32 + lq * 8];
#pragma unroll
    for (int j = 0; j < 4; ++j)
      bf[j] = *(const bf16x8*)&Bs[(wn + j * 16 + lr) * 32 + lq * 8];
#pragma unroll
    for (int i = 0; i < 4; ++i)
#pragma unroll
      for (int j = 0; j < 4; ++j)
        acc[i][j] = MFMA16(af[i], bf[j], acc[i][j]);
    __syncthreads();
  }

#pragma unroll
  for (int i = 0; i < 4; ++i) {
#pragma unroll
    for (int j = 0; j < 4; ++j) {
      int col = n0 + wn + j * 16 + lr;
      int tsel = col >> 10, rem = col & 1023;
      int h = rem >> 6, d = rem & 63;
      float bs = bias[col];
      int rowb = m0 + wm + i * 16 + lq * 4;
#pragma unroll
      for (int r = 0; r < 4; ++r) {
        int m = rowb + r;
        int b = m >> 11, sdx = m & 2047;
        __hip_bfloat16 v = __float2bfloat16(acc[i][j][r] + bs);
        long bh = (long)(b * 16 + h);
        if (tsel == 0)       Qo[(bh * 2048 + sdx) * 64 + d] = v;
        else if (tsel == 1)  Ko[(bh * 2048 + sdx) * 64 + d] = v;
        else                 Vt[(bh * 64 + d) * 2048 + sdx] = v;
      }
    }
  }
}

// ---------------- fused attention (round-0 structure, <=128-VGPR pipelined) ----------------
// Grid 1024x256; combo = blockIdx&7 -> (b,chunk) so each XCD sees one 4 MB K/V set.
// Diagnosis history: r0 = 128-VGPR allocator target serialized the 32-load K
// batches (260 us, 5% MfmaUtil); r1 = >128 live demand -> scratch spills
// (FETCH 34->428 MB, 426 us). Fix here: restructure so peak live <= ~128 arch
// VGPRs (ctx in AGPRs) while keeping 8-16 loads in flight per wave:
//   - K frags in 4-head groups (32 VGPR), double-buffered kA/kB, load g+1
//     while MFMAing g.
//   - V per-head (32 VGPR) double-buffered vA/vB: head0 issued before softmax
//     math, head1 after P-write (s dead), heads 2/3 inside PV as 0/1 retire.
//   - next-iter K group0 issued after P-write; latency hidden by barrier+PV.
// Raw s_barrier + lgkmcnt-only waits let register-destined loads ride across
// barriers. LDS 64 KB -> 2 blocks/CU -> 8 waves/CU.
__global__ __launch_bounds__(256, 2) void attn_kernel(
    const __hip_bfloat16* __restrict__ Q,
    const __hip_bfloat16* __restrict__ K,
    const __hip_bfloat16* __restrict__ Vt,
    __hip_bfloat16* __restrict__ part) {
  __shared__ __align__(16) __hip_bfloat16 Qs[16 * 16 * 64];  // 32 KB
  __shared__ __align__(16) __hip_bfloat16 P[16 * 16 * 64];   // 32 KB
  const int t = threadIdx.x, lane = t & 63, wv = t >> 6;
  const int lr = lane & 15, lq = lane >> 4;
  const int combo = blockIdx.x & 7;
  const int b = combo & 1, chunk = combo >> 1;
  const int q0 = (blockIdx.x >> 3) * 16;
  const int k0 = chunk * 512;
  const float c = 0.03125f * 1.44269504f;  // (1/sqrt(E)) * log2(e), E=1024
  const long bh16 = (long)(b * 16);

  // ---- stage Q tile: rows = h*16+q, 64 elems, granule-XOR swizzle ----
  {
    const int row = t;  // h = t>>4, q = t&15
    const __hip_bfloat16* gq = Q + ((bh16 + (t >> 4)) * 2048 + q0 + (t & 15)) * 64;
#pragma unroll
    for (int j = 0; j < 8; ++j) {
      bf16x8 v = *(const bf16x8*)(gq + j * 8);
      *(bf16x8*)&Qs[row * 64 + ((j ^ (row & 7)) << 3)] = v;
    }
  }

  const __hip_bfloat16* kbase = K + (bh16 * 2048 + k0 + wv * 16 + lr) * 64 + lq * 8;
  const __hip_bfloat16* vbase = Vt + ((bh16 + wv * 4) * 64 + lr) * 2048 + k0 + lq * 8;

  bf16x8 kA[8], kB[8], vA[8], vB[8];
  // prologue: K group 0 (heads 0-3, kk=k0) issued before the Qs barrier
#pragma unroll
  for (int j = 0; j < 4; ++j) {
    const __hip_bfloat16* kp = kbase + (long)j * (2048 * 64);
    kA[2 * j]     = *(const bf16x8*)kp;
    kA[2 * j + 1] = *(const bf16x8*)(kp + 32);
  }
  block_sync_lds();

  f32x4 ctx[4][4] = {};

  for (int kk = k0; kk < k0 + 512; kk += 64) {
    const long ko = (long)(kk - k0) * 64;  // element offset into K rows
    f32x4 s[16];

    // ---- QK^T: 4 groups of 4 heads, double-buffered K loads ----
#pragma unroll
    for (int g = 0; g < 4; ++g) {
      const bf16x8* cur = (g & 1) ? kB : kA;
      bf16x8* nxt = (g & 1) ? kA : kB;
      if (g < 3) {
#pragma unroll
        for (int j = 0; j < 4; ++j) {
          const __hip_bfloat16* kp = kbase + (long)((g + 1) * 4 + j) * (2048 * 64) + ko;
          nxt[2 * j]     = *(const bf16x8*)kp;
          nxt[2 * j + 1] = *(const bf16x8*)(kp + 32);
        }
      }
      __builtin_amdgcn_s_setprio(1);
#pragma unroll
      for (int j = 0; j < 4; ++j) {
        const int h = g * 4 + j;
        const int qrow = h * 16 + lr;
        bf16x8 qa = *(const bf16x8*)&Qs[qrow * 64 + ((lq ^ (lr & 7)) << 3)];
        bf16x8 qb = *(const bf16x8*)&Qs[qrow * 64 + (((lq + 4) ^ (lr & 7)) << 3)];
        f32x4 a = {};
        a = MFMA16(qa, cur[2 * j], a);
        a = MFMA16(qb, cur[2 * j + 1], a);
        s[h] = a;
      }
      __builtin_amdgcn_s_setprio(0);
    }

    // ---- issue V head 0 (latency hides under softmax VALU) ----
#pragma unroll
    for (int dt = 0; dt < 4; ++dt) {
      const __hip_bfloat16* vp = vbase + (long)dt * 16 * 2048 + (kk - k0);
      vA[dt * 2]     = *(const bf16x8*)vp;
      vA[dt * 2 + 1] = *(const bf16x8*)(vp + 32);
    }

    // ---- head-axis softmax per lane (no max-sub: |score*c| small) ----
    f32x4 sum = {0.f, 0.f, 0.f, 0.f};
#pragma unroll
    for (int h = 0; h < 16; ++h) {
#pragma unroll
      for (int r = 0; r < 4; ++r) s[h][r] = __builtin_amdgcn_exp2f(s[h][r] * c);
      sum += s[h];
    }
    f32x4 inv;
#pragma unroll
    for (int r = 0; r < 4; ++r) inv[r] = __builtin_amdgcn_rcpf(sum[r]);
    // P[h*16+q][k] swizzled; this wave's k-columns = wv*16 + lr
    const int gcol = (wv * 16 + lr) >> 3, coff = lr & 7;
#pragma unroll
    for (int h = 0; h < 16; ++h)
#pragma unroll
      for (int r = 0; r < 4; ++r) {
        int row = h * 16 + lq * 4 + r;
        P[row * 64 + ((gcol ^ (row & 7)) << 3) + coff] = __float2bfloat16(s[h][r] * inv[r]);
      }

    // ---- s now dead: issue next-iter K group0 (hidden by barrier + PV) ----
    if (kk + 64 < k0 + 512) {
#pragma unroll
      for (int j = 0; j < 4; ++j) {
        const __hip_bfloat16* kp = kbase + (long)j * (2048 * 64) + ko + 64 * 64;
        kA[2 * j]     = *(const bf16x8*)kp;
        kA[2 * j + 1] = *(const bf16x8*)(kp + 32);
      }
    }
    // ---- issue V head 1 (hidden by barrier + PV hh0) ----
#pragma unroll
    for (int dt = 0; dt < 4; ++dt) {
      const __hip_bfloat16* vp = vbase + (long)(64 * 2048) + (long)dt * 16 * 2048 + (kk - k0);
      vB[dt * 2]     = *(const bf16x8*)vp;
      vB[dt * 2 + 1] = *(const bf16x8*)(vp + 32);
    }
    block_sync_lds();

    // ---- PV: 4 heads, vA/vB double-buffered; heads 2/3 issued as 0/1 retire ----
    __builtin_amdgcn_s_setprio(1);
#pragma unroll
    for (int hh = 0; hh < 4; ++hh) {
      bf16x8* vcur = (hh & 1) ? vB : vA;
      const int h = wv * 4 + hh;
      const int prow = h * 16 + lr;
      bf16x8 pf0 = *(const bf16x8*)&P[prow * 64 + ((lq ^ (lr & 7)) << 3)];
      bf16x8 pf1 = *(const bf16x8*)&P[prow * 64 + (((lq + 4) ^ (lr & 7)) << 3)];
#pragma unroll
      for (int dt = 0; dt < 4; ++dt) {
        ctx[hh][dt] = MFMA16(pf0, vcur[dt * 2], ctx[hh][dt]);
        ctx[hh][dt] = MFMA16(pf1, vcur[dt * 2 + 1], ctx[hh][dt]);
      }
      if (hh < 2) {  // refill this buffer with head hh+2 (WAR handled by HW/compiler)
#pragma unroll
        for (int dt = 0; dt < 4; ++dt) {
          const __hip_bfloat16* vp =
              vbase + (long)(hh + 2) * (64 * 2048) + (long)dt * 16 * 2048 + (kk - k0);
          vcur[dt * 2]     = *(const bf16x8*)vp;
          vcur[dt * 2 + 1] = *(const bf16x8*)(vp + 32);
        }
      }
    }
    __builtin_amdgcn_s_setprio(0);
    block_sync_lds();
  }

  // ---- epilogue: ctx -> LDS (reuse P, same swizzle) -> coalesced wide store ----
  unsigned short* Pc = (unsigned short*)P;
#pragma unroll
  for (int hh = 0; hh < 4; ++hh) {
    int h = wv * 4 + hh;
#pragma unroll
    for (int dt = 0; dt < 4; ++dt) {
      int g = dt * 2 + (lr >> 3), off = lr & 7;
#pragma unroll
      for (int r = 0; r < 4; ++r) {
        int row = h * 16 + lq * 4 + r;
        Pc[row * 64 + ((g ^ (row & 7)) << 3) + off] = bf16bits(ctx[hh][dt][r]);
      }
    }
  }
  block_sync_lds();
  // part[chunk][b][q0..q0+15][h*64+d]: contiguous 32 KB per CTA.
  unsigned short* gbase = (unsigned short*)part + ((long)(chunk * 4096 + b * 2048 + q0)) * 1024;
#pragma unroll
  for (int j = 0; j < 8; ++j) {
    int gf = (j * 256 + t) * 8;            // flat over [16q][16h][64d]
    int q = gf >> 10, hd = gf & 1023;
    int h = hd >> 6, d = hd & 63;
    int row = h * 16 + q, gd = (d >> 3) & 7;
    u16x8 v = *(const u16x8*)&Pc[row * 64 + ((gd ^ (row & 7)) << 3)];
    *(u16x8*)&gbase[gf] = v;
  }
}

// ---------------- reduce 4 bf16 chunk partials + cast to bf16 ----------------
__global__ void reduce_cast_kernel(const unsigned short* __restrict__ part,
                                   __hip_bfloat16* __restrict__ dst) {
  int i = blockIdx.x * blockDim.x + threadIdx.x;  // 1M threads, 4 elems each
  const long S4 = (long)4096 * 1024 / 4;          // ushort4 units per chunk
  const ushort4* p = (const ushort4*)part;
  float sx = 0.f, sy = 0.f, sz = 0.f, sw = 0.f;
#pragma unroll
  for (int c = 0; c < 4; ++c) {
    ushort4 v = p[i + c * S4];
    sx += bf2f(v.x); sy += bf2f(v.y); sz += bf2f(v.z); sw += bf2f(v.w);
  }
  ushort4 u;
  u.x = bf16bits(sx); u.y = bf16bits(sy); u.z = bf16bits(sz); u.w = bf16bits(sw);
  ((ushort4*)dst)[i] = u;
}

// ---------------- GEMM2: out = ctxb @ woutb^T + b_out (fp32 out) ----------------
__global__ __launch_bounds__(256) void gemm_out_kernel(
    const __hip_bfloat16* __restrict__ A,   // [4096][1024]
    const __hip_bfloat16* __restrict__ B,   // [1024][1024]
    const float* __restrict__ bias,
    float* __restrict__ out) {
  const int K = 1024;
  __shared__ __align__(16) __hip_bfloat16 As[128 * 32];
  __shared__ __align__(16) __hip_bfloat16 Bs[128 * 32];
  const int t = threadIdx.x;
  const int lane = t & 63, wv = t >> 6;
  const int wm = (wv >> 1) * 64, wn = (wv & 1) * 64;
  const int lr = lane & 15, lq = lane >> 4;
  const int m0 = blockIdx.y * 128, n0 = blockIdx.x * 128;

  f32x4 acc[4][4] = {};

  const int arow = t >> 2;
  const int acol = (t & 3) * 8;
  const __hip_bfloat16* Ag = A + (long)(m0 + arow) * K + acol;
  const __hip_bfloat16* Bg = B + (long)(n0 + arow) * K + acol;
  __hip_bfloat16* Asl = As + t * 8;
  __hip_bfloat16* Bsl = Bs + t * 8;

  for (int kk = 0; kk < K; kk += 32) {
    gload16(Ag + kk, Asl);
    gload16(Ag + kk + 64 * K, Asl + 2048);
    gload16(Bg + kk, Bsl);
    gload16(Bg + kk + 64 * K, Bsl + 2048);
    __syncthreads();
    bf16x8 af[4], bf[4];
#pragma unroll
    for (int i = 0; i < 4; ++i)
      af[i] = *(const bf16x8*)&As[(wm + i * 16 + lr) * 32 + lq * 8];
#pragma unroll
    for (int j = 0; j < 4; ++j)
      bf[j] = *(const bf16x8*)&Bs[(wn + j * 16 + lr) * 32 + lq * 8];
#pragma unroll
    for (int i = 0; i < 4; ++i)
#pragma unroll
      for (int j = 0; j < 4; ++j)
        acc[i][j] = MFMA16(af[i], bf[j], acc[i][j]);
    __syncthreads();
  }

#pragma unroll
  for (int i = 0; i < 4; ++i) {
#pragma unroll
    for (int j = 0; j < 4; ++j) {
      int col = n0 + wn + j * 16 + lr;
      float bs = bias[col];
      int rowb = m0 + wm + i * 16 + lq * 4;
#pragma unroll
      for (int r = 0; r < 4; ++r) {
        out[(long)(rowb + r) * 1024 + col] = acc[i][j][r] + bs;
      }
    }
  }
}

extern "C" void kernel_launch(void* const* d_in, const int* in_sizes, int n_in,
                              void* d_out, int out_size, void* d_ws, size_t ws_size,
                              hipStream_t stream) {
  const float* x     = (const float*)d_in[0];
  const float* w_qkv = (const float*)d_in[1];
  const float* b_qkv = (const float*)d_in[2];
  const float* w_out = (const float*)d_in[3];
  const float* b_out = (const float*)d_in[4];
  float* out = (float*)d_out;
  char* ws = (char*)d_ws;

  // workspace layout (80 MB total)
  __hip_bfloat16* xb    = (__hip_bfloat16*)(ws);                       // 8 MB
  __hip_bfloat16* wqkvb = (__hip_bfloat16*)(ws + (8ul << 20));         // 6 MB
  __hip_bfloat16* woutb = (__hip_bfloat16*)(ws + (14ul << 20));        // 2 MB
  __hip_bfloat16* Qb    = (__hip_bfloat16*)(ws + (16ul << 20));        // 8 MB
  __hip_bfloat16* Kb    = (__hip_bfloat16*)(ws + (24ul << 20));        // 8 MB
  __hip_bfloat16* Vtb   = (__hip_bfloat16*)(ws + (32ul << 20));        // 8 MB
  __hip_bfloat16* partb = (__hip_bfloat16*)(ws + (40ul << 20));        // 32 MB (4 bf16 chunks)
  __hip_bfloat16* ctxb  = (__hip_bfloat16*)(ws + (72ul << 20));        // 8 MB

  cast_kernel<<<4096, 256, 0, stream>>>(x, xb, 4194304 / 4);
  cast_kernel<<<3072, 256, 0, stream>>>(w_qkv, wqkvb, 3145728 / 4);
  cast_kernel<<<1024, 256, 0, stream>>>(w_out, woutb, 1048576 / 4);
  gemm_qkv_kernel<<<dim3(24, 32), 256, 0, stream>>>(xb, wqkvb, b_qkv, Qb, Kb, Vtb);
  attn_kernel<<<1024, 256, 0, stream>>>(Qb, Kb, Vtb, partb);
  reduce_cast_kernel<<<4096, 256, 0, stream>>>((const unsigned short*)partb, ctxb);
  gemm_out_kernel<<<dim3(8, 32), 256, 0, stream>>>(ctxb, woutb, b_out, out);
}

// Round 4
// 349.639 us; speedup vs baseline: 1.6479x; 1.1833x over previous
//
#include <hip/hip_runtime.h>
#include <hip/hip_bf16.h>
#include <stdint.h>

typedef float  f32x4  __attribute__((ext_vector_type(4)));
typedef short  bf16x8 __attribute__((ext_vector_type(8)));
typedef unsigned short u16x8 __attribute__((ext_vector_type(8)));

#define MFMA16(a, b, c) __builtin_amdgcn_mfma_f32_16x16x32_bf16((a), (b), (c), 0, 0, 0)

__device__ __forceinline__ void gload16(const void* g, void* l) {
  __builtin_amdgcn_global_load_lds((const __attribute__((address_space(1))) void*)g,
                                   (__attribute__((address_space(3))) void*)l,
                                   16, 0, 0);
}

__device__ __forceinline__ unsigned short bf16bits(float f) {
  __hip_bfloat16 h = __float2bfloat16(f);
  return *(unsigned short*)&h;
}

__device__ __forceinline__ float bf2f(unsigned short u) {
  unsigned int x = ((unsigned int)u) << 16;
  return *(float*)&x;
}

// LDS-only barrier: drains DS ops, leaves global/LDS-DMA loads (vmcnt) in
// flight across the barrier. Counted vmcnt waits are inserted separately.
__device__ __forceinline__ void block_sync_lds() {
  asm volatile("s_waitcnt lgkmcnt(0)" ::: "memory");
  __builtin_amdgcn_s_barrier();
  asm volatile("" ::: "memory");
}

__device__ __forceinline__ void fence_order() { asm volatile("" ::: "memory"); }

// ---------------- fp32 -> bf16 cast, 4 elems/thread ----------------
__global__ void cast_kernel(const float* __restrict__ s, __hip_bfloat16* __restrict__ d, int n4) {
  int i = blockIdx.x * blockDim.x + threadIdx.x;
  if (i < n4) {
    float4 v = ((const float4*)s)[i];
    ushort4 u;
    u.x = bf16bits(v.x); u.y = bf16bits(v.y); u.z = bf16bits(v.z); u.w = bf16bits(v.w);
    ((ushort4*)d)[i] = u;
  }
}

// ---------------- GEMM1: qkv = xb @ wqkvb^T + b_qkv; scatter to Q,K,Vt (bf16) ----------------
__global__ __launch_bounds__(256) void gemm_qkv_kernel(
    const __hip_bfloat16* __restrict__ A,
    const __hip_bfloat16* __restrict__ B,
    const float* __restrict__ bias,
    __hip_bfloat16* __restrict__ Qo,
    __hip_bfloat16* __restrict__ Ko,
    __hip_bfloat16* __restrict__ Vt) {
  const int K = 1024;
  __shared__ __align__(16) __hip_bfloat16 As[128 * 32];
  __shared__ __align__(16) __hip_bfloat16 Bs[128 * 32];
  const int t = threadIdx.x;
  const int lane = t & 63, wv = t >> 6;
  const int wm = (wv >> 1) * 64, wn = (wv & 1) * 64;
  const int lr = lane & 15, lq = lane >> 4;
  const int m0 = blockIdx.y * 128, n0 = blockIdx.x * 128;

  f32x4 acc[4][4] = {};

  const int arow = t >> 2;
  const int acol = (t & 3) * 8;
  const __hip_bfloat16* Ag = A + (long)(m0 + arow) * K + acol;
  const __hip_bfloat16* Bg = B + (long)(n0 + arow) * K + acol;
  __hip_bfloat16* Asl = As + t * 8;
  __hip_bfloat16* Bsl = Bs + t * 8;

  for (int kk = 0; kk < K; kk += 32) {
    gload16(Ag + kk, Asl);
    gload16(Ag + kk + 64 * K, Asl + 2048);
    gload16(Bg + kk, Bsl);
    gload16(Bg + kk + 64 * K, Bsl + 2048);
    __syncthreads();
    bf16x8 af[4], bf[4];
#pragma unroll
    for (int i = 0; i < 4; ++i)
      af[i] = *(const bf16x8*)&As[(wm + i * 16 + lr) * 32 + lq * 8];
#pragma unroll
    for (int j = 0; j < 4; ++j)
      bf[j] = *(const bf16x8*)&Bs[(wn + j * 16 + lr) * 32 + lq * 8];
#pragma unroll
    for (int i = 0; i < 4; ++i)
#pragma unroll
      for (int j = 0; j < 4; ++j)
        acc[i][j] = MFMA16(af[i], bf[j], acc[i][j]);
    __syncthreads();
  }

#pragma unroll
  for (int i = 0; i < 4; ++i) {
#pragma unroll
    for (int j = 0; j < 4; ++j) {
      int col = n0 + wn + j * 16 + lr;
      int tsel = col >> 10, rem = col & 1023;
      int h = rem >> 6, d = rem & 63;
      float bs = bias[col];
      int rowb = m0 + wm + i * 16 + lq * 4;
#pragma unroll
      for (int r = 0; r < 4; ++r) {
        int m = rowb + r;
        int b = m >> 11, sdx = m & 2047;
        __hip_bfloat16 v = __float2bfloat16(acc[i][j][r] + bs);
        long bh = (long)(b * 16 + h);
        if (tsel == 0)       Qo[(bh * 2048 + sdx) * 64 + d] = v;
        else if (tsel == 1)  Ko[(bh * 2048 + sdx) * 64 + d] = v;
        else                 Vt[(bh * 64 + d) * 2048 + sdx] = v;
      }
    }
  }
}

// ---------------- fused attention v4: LDS-staged K/V via global_load_lds ----------------
// History: r0/r3 register-resident K/V streams stuck at ~260-270 us, MfmaUtil 5%,
// VGPR_Count pinned at 128 -> compiler serializes (r0) or spills (r1/r3) any
// structure needing >128 live regs. Fix: K/V staged to LDS with global_load_lds
// (zero VGPR cost, fire-and-forget), counted-vmcnt double-buffered pipeline.
// 512 thr / 8 waves, 2 heads per wave, Q in regs (16 VGPR). KSTEP=16.
// LDS: Ks dbuf 2x32K (granule-XOR swizzle via pre-swizzled global source),
// Vs 64K per 32-k pair, P 16K (same-wave round-trip, layout fix only),
// psum 10K padded f32x4. Total 154 KB -> 1 block/CU.
// Pipeline per (even,odd) step pair: even top stages next-K + pair-V;
// odd top stages next-even-K. vmcnt(8) at even end (K drained, V rides),
// vmcnt(4) before odd softmax barrier (V landed), vmcnt(0) at pair end.
// Peak live VGPRs ~100 -> no spills, nothing to serialize.
__global__ __launch_bounds__(512, 2) void attn_kernel(
    const __hip_bfloat16* __restrict__ Q,
    const __hip_bfloat16* __restrict__ K,
    const __hip_bfloat16* __restrict__ Vt,
    __hip_bfloat16* __restrict__ part) {
  __shared__ __align__(16) __hip_bfloat16 KsA[16 * 16 * 64];  // 32 KB, even tiles
  __shared__ __align__(16) __hip_bfloat16 KsB[16 * 16 * 64];  // 32 KB, odd tiles
  __shared__ __align__(16) __hip_bfloat16 Vs[16 * 64 * 32];   // 64 KB, one 32-k pair
  __shared__ __align__(16) __hip_bfloat16 P[16 * 16 * 32];    // 16 KB [h][q][32k]
  __shared__ __align__(16) float psum[8 * 16 * 20];           // 10 KB [w][k][20q-pad]

  const int t = threadIdx.x, lane = t & 63, wv = t >> 6;
  const int lr = lane & 15, lq = lane >> 4;
  const int h0 = wv * 2;  // this wave's two heads
  const int combo = blockIdx.x & 7;
  const int b = combo & 1, chunk = combo >> 1;
  const int q0 = (blockIdx.x >> 3) * 16;
  const int k0 = chunk * 512;
  const float c = 0.03125f * 1.44269504f;  // (1/sqrt(E)) * log2(e), E=1024
  const long bh16 = (long)(b * 16);

  // ---- K staging: Ks row rho=h*16+kl, 8 granules of 8 elems, slot = g^(rho&7).
  // global_load_lds writes linearly; the swizzle is applied on the SOURCE side.
  auto stageK = [&](__hip_bfloat16* dst, int kks) {
#pragma unroll
    for (int cc = 0; cc < 4; ++cc) {
      const int p = cc * 8192 + t * 16;      // byte slot
      const int rho = p >> 7;                // row
      const int hh = rho >> 4, kl = rho & 15;
      const int g = ((p >> 4) & 7) ^ (rho & 7);
      const __hip_bfloat16* src = K + ((bh16 + hh) * 2048 + kks + kl) * 64 + g * 8;
      gload16(src, (char*)dst + p);
    }
    fence_order();
  };
  // ---- V staging: Vs row rho=h*64+d (32 k elems), 4 granules, slot = g^((rho>>1)&3).
  auto stageV = [&](int kks) {
#pragma unroll
    for (int cc = 0; cc < 8; ++cc) {
      const int p = cc * 8192 + t * 16;
      const int rho = p >> 6;
      const int hh = rho >> 6, d = rho & 63;
      const int g = ((p >> 4) & 3) ^ ((rho >> 1) & 3);
      const __hip_bfloat16* src = Vt + ((bh16 + hh) * 64 + d) * 2048 + kks + g * 8;
      gload16(src, (char*)Vs + p);
    }
    fence_order();
  };

  // ---- Q fragments in registers (loaded once) ----
  bf16x8 qf[2][2];
#pragma unroll
  for (int hh = 0; hh < 2; ++hh)
#pragma unroll
    for (int dh = 0; dh < 2; ++dh)
      qf[hh][dh] = *(const bf16x8*)(Q + ((bh16 + h0 + hh) * 2048 + q0 + lr) * 64 + dh * 32 + lq * 8);

  stageK(KsA, k0);
  asm volatile("s_waitcnt vmcnt(0)" ::: "memory");
  block_sync_lds();

  f32x4 ctx[2][4] = {};
  f32x4 s[2];

  for (int pr = 0; pr < 16; ++pr) {
    const int kk = k0 + pr * 32;
    // ================= even step (par 0, reads KsA) =================
    stageK(KsB, kk + 16);
    stageV(kk);
    __builtin_amdgcn_s_setprio(1);
#pragma unroll
    for (int hh = 0; hh < 2; ++hh) {
      const int rho = (h0 + hh) * 16 + lr;
      const __hip_bfloat16* kr = KsA + rho * 64;
      bf16x8 kf0 = *(const bf16x8*)(kr + ((lq ^ (rho & 7)) << 3));
      bf16x8 kf1 = *(const bf16x8*)(kr + (((lq + 4) ^ (rho & 7)) << 3));
      f32x4 a = {};
      a = MFMA16(qf[hh][0], kf0, a);
      a = MFMA16(qf[hh][1], kf1, a);
      s[hh] = a;
    }
    __builtin_amdgcn_s_setprio(0);
    {
      f32x4 pp;
#pragma unroll
      for (int r = 0; r < 4; ++r) {
        s[0][r] = __builtin_amdgcn_exp2f(s[0][r] * c);
        s[1][r] = __builtin_amdgcn_exp2f(s[1][r] * c);
        pp[r] = s[0][r] + s[1][r];
      }
      *(f32x4*)&psum[wv * 320 + lr * 20 + lq * 4] = pp;
    }
    block_sync_lds();  // BAR-A: psum published
    {
      f32x4 tot = {};
#pragma unroll
      for (int w2 = 0; w2 < 8; ++w2)
        tot += *(const f32x4*)&psum[w2 * 320 + lr * 20 + lq * 4];
      f32x4 inv;
#pragma unroll
      for (int r = 0; r < 4; ++r) inv[r] = __builtin_amdgcn_rcpf(tot[r]);
#pragma unroll
      for (int hh = 0; hh < 2; ++hh)
#pragma unroll
        for (int r = 0; r < 4; ++r)
          P[(h0 + hh) * 512 + (lq * 4 + r) * 32 + lr] = __float2bfloat16(s[hh][r] * inv[r]);
    }
    asm volatile("s_waitcnt vmcnt(8)" ::: "memory");  // next-K landed; V still rides
    block_sync_lds();  // BAR-B

    // ================= odd step (par 1, reads KsB) =================
    if (pr < 15) stageK(KsA, kk + 32);
    __builtin_amdgcn_s_setprio(1);
#pragma unroll
    for (int hh = 0; hh < 2; ++hh) {
      const int rho = (h0 + hh) * 16 + lr;
      const __hip_bfloat16* kr = KsB + rho * 64;
      bf16x8 kf0 = *(const bf16x8*)(kr + ((lq ^ (rho & 7)) << 3));
      bf16x8 kf1 = *(const bf16x8*)(kr + (((lq + 4) ^ (rho & 7)) << 3));
      f32x4 a = {};
      a = MFMA16(qf[hh][0], kf0, a);
      a = MFMA16(qf[hh][1], kf1, a);
      s[hh] = a;
    }
    __builtin_amdgcn_s_setprio(0);
    {
      f32x4 pp;
#pragma unroll
      for (int r = 0; r < 4; ++r) {
        s[0][r] = __builtin_amdgcn_exp2f(s[0][r] * c);
        s[1][r] = __builtin_amdgcn_exp2f(s[1][r] * c);
        pp[r] = s[0][r] + s[1][r];
      }
      *(f32x4*)&psum[wv * 320 + lr * 20 + lq * 4] = pp;
    }
    // V must be fully in LDS before PV; K(next) stays in flight.
    if (pr < 15) asm volatile("s_waitcnt vmcnt(4)" ::: "memory");
    else         asm volatile("s_waitcnt vmcnt(0)" ::: "memory");
    block_sync_lds();  // BAR-A
    {
      f32x4 tot = {};
#pragma unroll
      for (int w2 = 0; w2 < 8; ++w2)
        tot += *(const f32x4*)&psum[w2 * 320 + lr * 20 + lq * 4];
      f32x4 inv;
#pragma unroll
      for (int r = 0; r < 4; ++r) inv[r] = __builtin_amdgcn_rcpf(tot[r]);
#pragma unroll
      for (int hh = 0; hh < 2; ++hh)
#pragma unroll
        for (int r = 0; r < 4; ++r)
          P[(h0 + hh) * 512 + (lq * 4 + r) * 32 + 16 + lr] = __float2bfloat16(s[hh][r] * inv[r]);
    }
    // ---- PV over the 32-k pair (P round-trip is same-wave; lgkm ordering only) ----
    __builtin_amdgcn_s_setprio(1);
#pragma unroll
    for (int hh = 0; hh < 2; ++hh) {
      bf16x8 pf = *(const bf16x8*)(P + (h0 + hh) * 512 + lr * 32 + lq * 8);
#pragma unroll
      for (int dt = 0; dt < 4; ++dt) {
        const int rho = (h0 + hh) * 64 + dt * 16 + lr;
        bf16x8 vfr = *(const bf16x8*)(Vs + rho * 32 + ((lq ^ ((rho >> 1) & 3)) << 3));
        ctx[hh][dt] = MFMA16(pf, vfr, ctx[hh][dt]);
      }
    }
    __builtin_amdgcn_s_setprio(0);
    asm volatile("s_waitcnt vmcnt(0)" ::: "memory");  // drain K(next even)
    block_sync_lds();  // BAR-B
  }

  // ---- epilogue: ctx -> LDS (reuse KsA, granule-XOR rows of 64) -> wide store ----
  unsigned short* Pc = (unsigned short*)KsA;
#pragma unroll
  for (int hh = 0; hh < 2; ++hh) {
    const int h = h0 + hh;
#pragma unroll
    for (int dt = 0; dt < 4; ++dt) {
      const int g = dt * 2 + (lr >> 3), off = lr & 7;
#pragma unroll
      for (int r = 0; r < 4; ++r) {
        const int row = h * 16 + lq * 4 + r;
        Pc[row * 64 + ((g ^ (row & 7)) << 3) + off] = bf16bits(ctx[hh][dt][r]);
      }
    }
  }
  block_sync_lds();
  // part[chunk][b][q0..q0+15][h*64+d]: contiguous 32 KB per CTA.
  unsigned short* gbase = (unsigned short*)part + ((long)(chunk * 4096 + b * 2048 + q0)) * 1024;
#pragma unroll
  for (int j = 0; j < 4; ++j) {
    int gf = (j * 512 + t) * 8;            // flat over [16q][16h][64d]
    int q = gf >> 10, hd = gf & 1023;
    int h = hd >> 6, d = hd & 63;
    int row = h * 16 + q, gd = (d >> 3) & 7;
    u16x8 v = *(const u16x8*)&Pc[row * 64 + ((gd ^ (row & 7)) << 3)];
    *(u16x8*)&gbase[gf] = v;
  }
}

// ---------------- reduce 4 bf16 chunk partials + cast to bf16 ----------------
__global__ void reduce_cast_kernel(const unsigned short* __restrict__ part,
                                   __hip_bfloat16* __restrict__ dst) {
  int i = blockIdx.x * blockDim.x + threadIdx.x;  // 1M threads, 4 elems each
  const long S4 = (long)4096 * 1024 / 4;          // ushort4 units per chunk
  const ushort4* p = (const ushort4*)part;
  float sx = 0.f, sy = 0.f, sz = 0.f, sw = 0.f;
#pragma unroll
  for (int c = 0; c < 4; ++c) {
    ushort4 v = p[i + c * S4];
    sx += bf2f(v.x); sy += bf2f(v.y); sz += bf2f(v.z); sw += bf2f(v.w);
  }
  ushort4 u;
  u.x = bf16bits(sx); u.y = bf16bits(sy); u.z = bf16bits(sz); u.w = bf16bits(sw);
  ((ushort4*)dst)[i] = u;
}

// ---------------- GEMM2: out = ctxb @ woutb^T + b_out (fp32 out) ----------------
__global__ __launch_bounds__(256) void gemm_out_kernel(
    const __hip_bfloat16* __restrict__ A,   // [4096][1024]
    const __hip_bfloat16* __restrict__ B,   // [1024][1024]
    const float* __restrict__ bias,
    float* __restrict__ out) {
  const int K = 1024;
  __shared__ __align__(16) __hip_bfloat16 As[128 * 32];
  __shared__ __align__(16) __hip_bfloat16 Bs[128 * 32];
  const int t = threadIdx.x;
  const int lane = t & 63, wv = t >> 6;
  const int wm = (wv >> 1) * 64, wn = (wv & 1) * 64;
  const int lr = lane & 15, lq = lane >> 4;
  const int m0 = blockIdx.y * 128, n0 = blockIdx.x * 128;

  f32x4 acc[4][4] = {};

  const int arow = t >> 2;
  const int acol = (t & 3) * 8;
  const __hip_bfloat16* Ag = A + (long)(m0 + arow) * K + acol;
  const __hip_bfloat16* Bg = B + (long)(n0 + arow) * K + acol;
  __hip_bfloat16* Asl = As + t * 8;
  __hip_bfloat16* Bsl = Bs + t * 8;

  for (int kk = 0; kk < K; kk += 32) {
    gload16(Ag + kk, Asl);
    gload16(Ag + kk + 64 * K, Asl + 2048);
    gload16(Bg + kk, Bsl);
    gload16(Bg + kk + 64 * K, Bsl + 2048);
    __syncthreads();
    bf16x8 af[4], bf[4];
#pragma unroll
    for (int i = 0; i < 4; ++i)
      af[i] = *(const bf16x8*)&As[(wm + i * 16 + lr) * 32 + lq * 8];
#pragma unroll
    for (int j = 0; j < 4; ++j)
      bf[j] = *(const bf16x8*)&Bs[(wn + j * 16 + lr) * 32 + lq * 8];
#pragma unroll
    for (int i = 0; i < 4; ++i)
#pragma unroll
      for (int j = 0; j < 4; ++j)
        acc[i][j] = MFMA16(af[i], bf[j], acc[i][j]);
    __syncthreads();
  }

#pragma unroll
  for (int i = 0; i < 4; ++i) {
#pragma unroll
    for (int j = 0; j < 4; ++j) {
      int col = n0 + wn + j * 16 + lr;
      float bs = bias[col];
      int rowb = m0 + wm + i * 16 + lq * 4;
#pragma unroll
      for (int r = 0; r < 4; ++r) {
        out[(long)(rowb + r) * 1024 + col] = acc[i][j][r] + bs;
      }
    }
  }
}

extern "C" void kernel_launch(void* const* d_in, const int* in_sizes, int n_in,
                              void* d_out, int out_size, void* d_ws, size_t ws_size,
                              hipStream_t stream) {
  const float* x     = (const float*)d_in[0];
  const float* w_qkv = (const float*)d_in[1];
  const float* b_qkv = (const float*)d_in[2];
  const float* w_out = (const float*)d_in[3];
  const float* b_out = (const float*)d_in[4];
  float* out = (float*)d_out;
  char* ws = (char*)d_ws;

  // workspace layout (80 MB total)
  __hip_bfloat16* xb    = (__hip_bfloat16*)(ws);                       // 8 MB
  __hip_bfloat16* wqkvb = (__hip_bfloat16*)(ws + (8ul << 20));         // 6 MB
  __hip_bfloat16* woutb = (__hip_bfloat16*)(ws + (14ul << 20));        // 2 MB
  __hip_bfloat16* Qb    = (__hip_bfloat16*)(ws + (16ul << 20));        // 8 MB
  __hip_bfloat16* Kb    = (__hip_bfloat16*)(ws + (24ul << 20));        // 8 MB
  __hip_bfloat16* Vtb   = (__hip_bfloat16*)(ws + (32ul << 20));        // 8 MB
  __hip_bfloat16* partb = (__hip_bfloat16*)(ws + (40ul << 20));        // 32 MB (4 bf16 chunks)
  __hip_bfloat16* ctxb  = (__hip_bfloat16*)(ws + (72ul << 20));        // 8 MB

  cast_kernel<<<4096, 256, 0, stream>>>(x, xb, 4194304 / 4);
  cast_kernel<<<3072, 256, 0, stream>>>(w_qkv, wqkvb, 3145728 / 4);
  cast_kernel<<<1024, 256, 0, stream>>>(w_out, woutb, 1048576 / 4);
  gemm_qkv_kernel<<<dim3(24, 32), 256, 0, stream>>>(xb, wqkvb, b_qkv, Qb, Kb, Vtb);
  attn_kernel<<<1024, 512, 0, stream>>>(Qb, Kb, Vtb, partb);
  reduce_cast_kernel<<<4096, 256, 0, stream>>>((const unsigned short*)partb, ctxb);
  gemm_out_kernel<<<dim3(8, 32), 256, 0, stream>>>(ctxb, woutb, b_out, out);
}

// Round 5
// 346.138 us; speedup vs baseline: 1.6645x; 1.0101x over previous
//
#include <hip/hip_runtime.h>
#include <hip/hip_bf16.h>
#include <stdint.h>

typedef float  f32x4  __attribute__((ext_vector_type(4)));
typedef short  bf16x8 __attribute__((ext_vector_type(8)));
typedef short  bf16x4 __attribute__((ext_vector_type(4)));
typedef unsigned short u16x8 __attribute__((ext_vector_type(8)));

#define MFMA16(a, b, c) __builtin_amdgcn_mfma_f32_16x16x32_bf16((a), (b), (c), 0, 0, 0)

__device__ __forceinline__ void gload16(const void* g, void* l) {
  __builtin_amdgcn_global_load_lds((const __attribute__((address_space(1))) void*)g,
                                   (__attribute__((address_space(3))) void*)l,
                                   16, 0, 0);
}

__device__ __forceinline__ unsigned short bf16bits(float f) {
  __hip_bfloat16 h = __float2bfloat16(f);
  return *(unsigned short*)&h;
}

__device__ __forceinline__ float bf2f(unsigned short u) {
  unsigned int x = ((unsigned int)u) << 16;
  return *(float*)&x;
}

// LDS-only barrier: drains DS ops, leaves global/LDS-DMA loads (vmcnt) in
// flight across the barrier. Counted vmcnt waits are inserted separately.
__device__ __forceinline__ void block_sync_lds() {
  asm volatile("s_waitcnt lgkmcnt(0)" ::: "memory");
  __builtin_amdgcn_s_barrier();
  asm volatile("" ::: "memory");
}

__device__ __forceinline__ void fence_order() { asm volatile("" ::: "memory"); }

// ---------------- fp32 -> bf16 cast, 4 elems/thread ----------------
__global__ void cast_kernel(const float* __restrict__ s, __hip_bfloat16* __restrict__ d, int n4) {
  int i = blockIdx.x * blockDim.x + threadIdx.x;
  if (i < n4) {
    float4 v = ((const float4*)s)[i];
    ushort4 u;
    u.x = bf16bits(v.x); u.y = bf16bits(v.y); u.z = bf16bits(v.z); u.w = bf16bits(v.w);
    ((ushort4*)d)[i] = u;
  }
}

// ---------------- GEMM1: qkv = xb @ wqkvb^T + b_qkv; scatter to Q,K,Vt (bf16) ----------------
__global__ __launch_bounds__(256) void gemm_qkv_kernel(
    const __hip_bfloat16* __restrict__ A,
    const __hip_bfloat16* __restrict__ B,
    const float* __restrict__ bias,
    __hip_bfloat16* __restrict__ Qo,
    __hip_bfloat16* __restrict__ Ko,
    __hip_bfloat16* __restrict__ Vt) {
  const int K = 1024;
  __shared__ __align__(16) __hip_bfloat16 As[128 * 32];
  __shared__ __align__(16) __hip_bfloat16 Bs[128 * 32];
  const int t = threadIdx.x;
  const int lane = t & 63, wv = t >> 6;
  const int wm = (wv >> 1) * 64, wn = (wv & 1) * 64;
  const int lr = lane & 15, lq = lane >> 4;
  const int m0 = blockIdx.y * 128, n0 = blockIdx.x * 128;

  f32x4 acc[4][4] = {};

  const int arow = t >> 2;
  const int acol = (t & 3) * 8;
  const __hip_bfloat16* Ag = A + (long)(m0 + arow) * K + acol;
  const __hip_bfloat16* Bg = B + (long)(n0 + arow) * K + acol;
  __hip_bfloat16* Asl = As + t * 8;
  __hip_bfloat16* Bsl = Bs + t * 8;

  for (int kk = 0; kk < K; kk += 32) {
    gload16(Ag + kk, Asl);
    gload16(Ag + kk + 64 * K, Asl + 2048);
    gload16(Bg + kk, Bsl);
    gload16(Bg + kk + 64 * K, Bsl + 2048);
    __syncthreads();
    bf16x8 af[4], bf[4];
#pragma unroll
    for (int i = 0; i < 4; ++i)
      af[i] = *(const bf16x8*)&As[(wm + i * 16 + lr) * 32 + lq * 8];
#pragma unroll
    for (int j = 0; j < 4; ++j)
      bf[j] = *(const bf16x8*)&Bs[(wn + j * 16 + lr) * 32 + lq * 8];
#pragma unroll
    for (int i = 0; i < 4; ++i)
#pragma unroll
      for (int j = 0; j < 4; ++j)
        acc[i][j] = MFMA16(af[i], bf[j], acc[i][j]);
    __syncthreads();
  }

#pragma unroll
  for (int i = 0; i < 4; ++i) {
#pragma unroll
    for (int j = 0; j < 4; ++j) {
      int col = n0 + wn + j * 16 + lr;
      int tsel = col >> 10, rem = col & 1023;
      int h = rem >> 6, d = rem & 63;
      float bs = bias[col];
      int rowb = m0 + wm + i * 16 + lq * 4;
#pragma unroll
      for (int r = 0; r < 4; ++r) {
        int m = rowb + r;
        int b = m >> 11, sdx = m & 2047;
        __hip_bfloat16 v = __float2bfloat16(acc[i][j][r] + bs);
        long bh = (long)(b * 16 + h);
        if (tsel == 0)       Qo[(bh * 2048 + sdx) * 64 + d] = v;
        else if (tsel == 1)  Ko[(bh * 2048 + sdx) * 64 + d] = v;
        else                 Vt[(bh * 64 + d) * 2048 + sdx] = v;
      }
    }
  }
}

// ---------------- fused attention v5: transposed-score, 2 blocks/CU ----------------
// r4 diagnosis: LDS-pipe bound (~290 KB through one 128B/cyc pipe per 16k-step;
// psum all-read 72KB + 4-way-conflicted scalar P writes = 13.7M conflicts) at
// 1 block/CU (zero TLP). v5 changes:
//  (1) S^T = mfma(A=Kfrag, B=Qfrag): lane holds 4 consecutive k at fixed q ->
//      P write = 1 b64/head into [h][q][16k] (32B rows, conflict-free);
//      PV = mfma(A=V^T frag, B=Pfrag), clean b128 reads, upper-16k zero-padded.
//  (2) wave0-reduce for the 16-head sum: 8 partials read by wave0 only, inv
//      (rcp) published once -> exchange 72KB -> ~18KB per step.
//  (3) single-buffered K (32KB) and V (32KB) tiles, 16k step; stage issued
//      right after the last-reader barrier, counted vmcnt(4) gives each load
//      >= half a step to land. LDS = 32+32+8+8 KB = 81920 B exactly
//      -> 2 blocks/CU, 16 waves/CU: TLP overlaps barrier/latency stalls.
// Wave owns 2 heads (QK and PV). Q in regs (16 VGPR). Zero VGPR staging.
__global__ __launch_bounds__(512, 4) void attn_kernel(
    const __hip_bfloat16* __restrict__ Q,
    const __hip_bfloat16* __restrict__ K,
    const __hip_bfloat16* __restrict__ Vt,
    __hip_bfloat16* __restrict__ part) {
  __shared__ __align__(16) __hip_bfloat16 Ks[16 * 16 * 64];  // 32 KB [h][16k][64d], granule-XOR
  __shared__ __align__(16) __hip_bfloat16 Vs[16 * 64 * 16];  // 32 KB [h][64d][16k], linear
  __shared__ __align__(16) __hip_bfloat16 P[16 * 16 * 16];   // 8 KB  [h][q][16k]
  __shared__ __align__(16) float psum[8 * 16 * 16];          // 8 KB  [w][q][16k]; inv in w=0

  const int t = threadIdx.x, lane = t & 63, wv = t >> 6;
  const int lr = lane & 15, lq = lane >> 4;
  const int h0 = wv * 2;  // this wave's two heads
  const int combo = blockIdx.x & 7;
  const int b = combo & 1, chunk = combo >> 1;
  const int q0 = (blockIdx.x >> 3) * 16;
  const int k0 = chunk * 512;
  const float c = 0.03125f * 1.44269504f;  // (1/sqrt(E)) * log2(e), E=1024
  const long bh16 = (long)(b * 16);

  // K staging: row rho = h*16+kl (128B), 8 granules; LDS linear, swizzle on SOURCE:
  // slot gs holds source granule g = gs ^ (rho&7).
  auto stageK = [&](int kks) {
#pragma unroll
    for (int cc = 0; cc < 4; ++cc) {
      const int p = cc * 8192 + t * 16;
      const int rho = p >> 7;
      const int hh = rho >> 4, kl = rho & 15;
      const int g = ((p >> 4) & 7) ^ (rho & 7);
      const __hip_bfloat16* src = K + ((bh16 + hh) * 2048 + kks + kl) * 64 + g * 8;
      gload16(src, (char*)Ks + p);
    }
    fence_order();
  };
  // V staging: row rho = h*64+d (32B, 2 granules), linear both sides.
  auto stageV = [&](int kks) {
#pragma unroll
    for (int cc = 0; cc < 4; ++cc) {
      const int p = cc * 8192 + t * 16;
      const int rho = p >> 5;
      const int hh = rho >> 6, d = rho & 63;
      const int g = (p >> 4) & 1;
      const __hip_bfloat16* src = Vt + ((bh16 + hh) * 64 + d) * 2048 + kks + g * 8;
      gload16(src, (char*)Vs + p);
    }
    fence_order();
  };

  // Q fragments (B-operand: lane holds Q[q=lr][d = dh*32 + lq*8 ..+8])
  bf16x8 qf[2][2];
#pragma unroll
  for (int hh = 0; hh < 2; ++hh)
#pragma unroll
    for (int dh = 0; dh < 2; ++dh)
      qf[hh][dh] = *(const bf16x8*)(Q + ((bh16 + h0 + hh) * 2048 + q0 + lr) * 64 + dh * 32 + lq * 8);

  stageK(k0);
  stageV(k0);
  asm volatile("s_waitcnt vmcnt(0)" ::: "memory");
  block_sync_lds();

  f32x4 ctx[2][4] = {};
  const bf16x8 zf = {};

  for (int kt = 0; kt < 32; ++kt) {
    // entry: Ks = K(kt) landed (vmcnt below), Vs = V(kt) (landed later), K older than V.
    asm volatile("s_waitcnt vmcnt(4)" ::: "memory");  // K(kt) done; V(kt) may ride
    block_sync_lds();  // BAR-A: K visible to all

    // ---- QK^T transposed: ST[k][q], lane holds (k = lq*4+r, q = lr) ----
    f32x4 s[2];
    __builtin_amdgcn_s_setprio(1);
#pragma unroll
    for (int hh = 0; hh < 2; ++hh) {
      const int rho = (h0 + hh) * 16 + lr;  // K row = k index lr
      const __hip_bfloat16* kr = Ks + rho * 64;
      bf16x8 kf0 = *(const bf16x8*)(kr + ((lq ^ (rho & 7)) << 3));
      bf16x8 kf1 = *(const bf16x8*)(kr + (((lq + 4) ^ (rho & 7)) << 3));
      f32x4 a = {};
      a = MFMA16(kf0, qf[hh][0], a);
      a = MFMA16(kf1, qf[hh][1], a);
      s[hh] = a;
    }
    __builtin_amdgcn_s_setprio(0);

    // ---- exp + 2-head partial; publish ----
    {
      f32x4 pp;
#pragma unroll
      for (int r = 0; r < 4; ++r) {
        s[0][r] = __builtin_amdgcn_exp2f(s[0][r] * c);
        s[1][r] = __builtin_amdgcn_exp2f(s[1][r] * c);
        pp[r] = s[0][r] + s[1][r];
      }
      *(f32x4*)&psum[wv * 256 + lr * 16 + lq * 4] = pp;
    }
    block_sync_lds();  // BAR-B: partials visible; all Ks reads done

    // ---- stage next K (safe: BAR-B) while wave0 reduces ----
    if (kt < 31) stageK(k0 + (kt + 1) * 16);
    if (wv == 0) {
      f32x4 tot = {};
#pragma unroll
      for (int w2 = 0; w2 < 8; ++w2)
        tot += *(const f32x4*)&psum[w2 * 256 + lr * 16 + lq * 4];
      f32x4 inv;
#pragma unroll
      for (int r = 0; r < 4; ++r) inv[r] = __builtin_amdgcn_rcpf(tot[r]);
      *(f32x4*)&psum[lr * 16 + lq * 4] = inv;  // overwrite w=0 partial (already consumed)
    }
    block_sync_lds();  // BAR-C: inv visible

    // ---- normalize + P write: one b64 per head (4 consecutive k) ----
    {
      f32x4 inv = *(const f32x4*)&psum[lr * 16 + lq * 4];
#pragma unroll
      for (int hh = 0; hh < 2; ++hh) {
        bf16x4 pk;
#pragma unroll
        for (int r = 0; r < 4; ++r) pk[r] = (short)bf16bits(s[hh][r] * inv[r]);
        *(bf16x4*)((char*)P + (h0 + hh) * 512 + lr * 32 + lq * 8) = pk;
      }
    }

    // ---- V(kt) must be landed (K(kt+1) keeps flying) ----
    if (kt < 31) asm volatile("s_waitcnt vmcnt(4)" ::: "memory");
    else         asm volatile("s_waitcnt vmcnt(0)" ::: "memory");
    block_sync_lds();  // BAR-D: V visible

    // ---- PV transposed: ctx^T[d][q] += V^T[d][k] * P[k][q]; upper 16k zero ----
    __builtin_amdgcn_s_setprio(1);
#pragma unroll
    for (int hh = 0; hh < 2; ++hh) {
      const int h = h0 + hh;
      bf16x8 pf = *(const bf16x8*)((char*)P + h * 512 + lr * 32 + (lq & 1) * 16);
      if (lq >= 2) pf = zf;
#pragma unroll
      for (int dt = 0; dt < 4; ++dt) {
        bf16x8 vf = *(const bf16x8*)((char*)Vs + h * 2048 + (dt * 16 + lr) * 32 + (lq & 1) * 16);
        ctx[hh][dt] = MFMA16(vf, pf, ctx[hh][dt]);
      }
    }
    __builtin_amdgcn_s_setprio(0);
    block_sync_lds();  // BAR-E: all Vs reads done

    if (kt < 31) stageV(k0 + (kt + 1) * 16);
  }

  // ---- epilogue: ctx^T -> LDS (reuse Ks as [16q][1024hd], 16B-XOR by q) -> wide store ----
  unsigned short* Pc = (unsigned short*)Ks;
#pragma unroll
  for (int hh = 0; hh < 2; ++hh) {
    const int h = h0 + hh;
#pragma unroll
    for (int dt = 0; dt < 4; ++dt) {
      bf16x4 pk;
#pragma unroll
      for (int r = 0; r < 4; ++r) pk[r] = (short)bf16bits(ctx[hh][dt][r]);
      const int o = h * 128 + dt * 32 + lq * 8;                 // byte-in-row, d = dt*16+lq*4+r
      *(bf16x4*)((char*)Pc + lr * 2048 + (o ^ ((lr & 7) << 4))) = pk;
    }
  }
  block_sync_lds();
  // part[chunk][b][q0..q0+15][h*64+d]: contiguous 32 KB per CTA.
  unsigned short* gbase = (unsigned short*)part + ((long)(chunk * 4096 + b * 2048 + q0)) * 1024;
#pragma unroll
  for (int j = 0; j < 4; ++j) {
    int gf = (j * 512 + t) * 8;            // flat over [16q][16h*64d]
    int q = gf >> 10, hd = gf & 1023;
    u16x8 v = *(const u16x8*)((char*)Pc + q * 2048 + ((hd * 2) ^ ((q & 7) << 4)));
    *(u16x8*)&gbase[gf] = v;
  }
}

// ---------------- reduce 4 bf16 chunk partials + cast to bf16 ----------------
__global__ void reduce_cast_kernel(const unsigned short* __restrict__ part,
                                   __hip_bfloat16* __restrict__ dst) {
  int i = blockIdx.x * blockDim.x + threadIdx.x;  // 1M threads, 4 elems each
  const long S4 = (long)4096 * 1024 / 4;          // ushort4 units per chunk
  const ushort4* p = (const ushort4*)part;
  float sx = 0.f, sy = 0.f, sz = 0.f, sw = 0.f;
#pragma unroll
  for (int c = 0; c < 4; ++c) {
    ushort4 v = p[i + c * S4];
    sx += bf2f(v.x); sy += bf2f(v.y); sz += bf2f(v.z); sw += bf2f(v.w);
  }
  ushort4 u;
  u.x = bf16bits(sx); u.y = bf16bits(sy); u.z = bf16bits(sz); u.w = bf16bits(sw);
  ((ushort4*)dst)[i] = u;
}

// ---------------- GEMM2: out = ctxb @ woutb^T + b_out (fp32 out) ----------------
__global__ __launch_bounds__(256) void gemm_out_kernel(
    const __hip_bfloat16* __restrict__ A,   // [4096][1024]
    const __hip_bfloat16* __restrict__ B,   // [1024][1024]
    const float* __restrict__ bias,
    float* __restrict__ out) {
  const int K = 1024;
  __shared__ __align__(16) __hip_bfloat16 As[128 * 32];
  __shared__ __align__(16) __hip_bfloat16 Bs[128 * 32];
  const int t = threadIdx.x;
  const int lane = t & 63, wv = t >> 6;
  const int wm = (wv >> 1) * 64, wn = (wv & 1) * 64;
  const int lr = lane & 15, lq = lane >> 4;
  const int m0 = blockIdx.y * 128, n0 = blockIdx.x * 128;

  f32x4 acc[4][4] = {};

  const int arow = t >> 2;
  const int acol = (t & 3) * 8;
  const __hip_bfloat16* Ag = A + (long)(m0 + arow) * K + acol;
  const __hip_bfloat16* Bg = B + (long)(n0 + arow) * K + acol;
  __hip_bfloat16* Asl = As + t * 8;
  __hip_bfloat16* Bsl = Bs + t * 8;

  for (int kk = 0; kk < K; kk += 32) {
    gload16(Ag + kk, Asl);
    gload16(Ag + kk + 64 * K, Asl + 2048);
    gload16(Bg + kk, Bsl);
    gload16(Bg + kk + 64 * K, Bsl + 2048);
    __syncthreads();
    bf16x8 af[4], bf[4];
#pragma unroll
    for (int i = 0; i < 4; ++i)
      af[i] = *(const bf16x8*)&As[(wm + i * 16 + lr) * 32 + lq * 8];
#pragma unroll
    for (int j = 0; j < 4; ++j)
      bf[j] = *(const bf16x8*)&Bs[(wn + j * 16 + lr) * 32 + lq * 8];
#pragma unroll
    for (int i = 0; i < 4; ++i)
#pragma unroll
      for (int j = 0; j < 4; ++j)
        acc[i][j] = MFMA16(af[i], bf[j], acc[i][j]);
    __syncthreads();
  }

#pragma unroll
  for (int i = 0; i < 4; ++i) {
#pragma unroll
    for (int j = 0; j < 4; ++j) {
      int col = n0 + wn + j * 16 + lr;
      float bs = bias[col];
      int rowb = m0 + wm + i * 16 + lq * 4;
#pragma unroll
      for (int r = 0; r < 4; ++r) {
        out[(long)(rowb + r) * 1024 + col] = acc[i][j][r] + bs;
      }
    }
  }
}

extern "C" void kernel_launch(void* const* d_in, const int* in_sizes, int n_in,
                              void* d_out, int out_size, void* d_ws, size_t ws_size,
                              hipStream_t stream) {
  const float* x     = (const float*)d_in[0];
  const float* w_qkv = (const float*)d_in[1];
  const float* b_qkv = (const float*)d_in[2];
  const float* w_out = (const float*)d_in[3];
  const float* b_out = (const float*)d_in[4];
  float* out = (float*)d_out;
  char* ws = (char*)d_ws;

  // workspace layout (80 MB total)
  __hip_bfloat16* xb    = (__hip_bfloat16*)(ws);                       // 8 MB
  __hip_bfloat16* wqkvb = (__hip_bfloat16*)(ws + (8ul << 20));         // 6 MB
  __hip_bfloat16* woutb = (__hip_bfloat16*)(ws + (14ul << 20));        // 2 MB
  __hip_bfloat16* Qb    = (__hip_bfloat16*)(ws + (16ul << 20));        // 8 MB
  __hip_bfloat16* Kb    = (__hip_bfloat16*)(ws + (24ul << 20));        // 8 MB
  __hip_bfloat16* Vtb   = (__hip_bfloat16*)(ws + (32ul << 20));        // 8 MB
  __hip_bfloat16* partb = (__hip_bfloat16*)(ws + (40ul << 20));        // 32 MB (4 bf16 chunks)
  __hip_bfloat16* ctxb  = (__hip_bfloat16*)(ws + (72ul << 20));        // 8 MB

  cast_kernel<<<4096, 256, 0, stream>>>(x, xb, 4194304 / 4);
  cast_kernel<<<3072, 256, 0, stream>>>(w_qkv, wqkvb, 3145728 / 4);
  cast_kernel<<<1024, 256, 0, stream>>>(w_out, woutb, 1048576 / 4);
  gemm_qkv_kernel<<<dim3(24, 32), 256, 0, stream>>>(xb, wqkvb, b_qkv, Qb, Kb, Vtb);
  attn_kernel<<<1024, 512, 0, stream>>>(Qb, Kb, Vtb, partb);
  reduce_cast_kernel<<<4096, 256, 0, stream>>>((const unsigned short*)partb, ctxb);
  gemm_out_kernel<<<dim3(8, 32), 256, 0, stream>>>(ctxb, woutb, b_out, out);
}

// Round 6
// 320.825 us; speedup vs baseline: 1.7959x; 1.0789x over previous
//
#include <hip/hip_runtime.h>
#include <hip/hip_bf16.h>
#include <stdint.h>

typedef float  f32x4  __attribute__((ext_vector_type(4)));
typedef short  bf16x8 __attribute__((ext_vector_type(8)));
typedef short  bf16x4 __attribute__((ext_vector_type(4)));
typedef unsigned short u16x8 __attribute__((ext_vector_type(8)));

#define MFMA16(a, b, c) __builtin_amdgcn_mfma_f32_16x16x32_bf16((a), (b), (c), 0, 0, 0)

// 16x16x16 bf16 MFMA: A/B = 4 bf16/lane (k = (lane>>4)*4 + reg), C/D standard 16x16.
#if __has_builtin(__builtin_amdgcn_mfma_f32_16x16x16bf16_1k)
#define MFMA16K16(a, b, c) __builtin_amdgcn_mfma_f32_16x16x16bf16_1k((a), (b), (c), 0, 0, 0)
#else
__device__ __forceinline__ f32x4 mfma16k16_asm(bf16x4 a, bf16x4 b, f32x4 c) {
  f32x4 d;
  asm volatile("v_mfma_f32_16x16x16_bf16 %0, %1, %2, %3"
               : "=v"(d) : "v"(a), "v"(b), "v"(c));
  return d;
}
#define MFMA16K16(a, b, c) mfma16k16_asm((a), (b), (c))
#endif

__device__ __forceinline__ void gload16(const void* g, void* l) {
  __builtin_amdgcn_global_load_lds((const __attribute__((address_space(1))) void*)g,
                                   (__attribute__((address_space(3))) void*)l,
                                   16, 0, 0);
}

__device__ __forceinline__ unsigned short bf16bits(float f) {
  __hip_bfloat16 h = __float2bfloat16(f);
  return *(unsigned short*)&h;
}

__device__ __forceinline__ float bf2f(unsigned short u) {
  unsigned int x = ((unsigned int)u) << 16;
  return *(float*)&x;
}

// LDS-only barrier: drains DS ops, leaves LDS-DMA (vmcnt) in flight.
__device__ __forceinline__ void block_sync_lds() {
  asm volatile("s_waitcnt lgkmcnt(0)" ::: "memory");
  __builtin_amdgcn_s_barrier();
  asm volatile("" ::: "memory");
}

__device__ __forceinline__ void fence_order() { asm volatile("" ::: "memory"); }

// ---------------- fp32 -> bf16 cast, 4 elems/thread ----------------
__global__ void cast_kernel(const float* __restrict__ s, __hip_bfloat16* __restrict__ d, int n4) {
  int i = blockIdx.x * blockDim.x + threadIdx.x;
  if (i < n4) {
    float4 v = ((const float4*)s)[i];
    ushort4 u;
    u.x = bf16bits(v.x); u.y = bf16bits(v.y); u.z = bf16bits(v.z); u.w = bf16bits(v.w);
    ((ushort4*)d)[i] = u;
  }
}

// ---------------- GEMM1: qkv = xb @ wqkvb^T + b_qkv; scatter to Q,K,Vt (bf16) ----------------
__global__ __launch_bounds__(256) void gemm_qkv_kernel(
    const __hip_bfloat16* __restrict__ A,
    const __hip_bfloat16* __restrict__ B,
    const float* __restrict__ bias,
    __hip_bfloat16* __restrict__ Qo,
    __hip_bfloat16* __restrict__ Ko,
    __hip_bfloat16* __restrict__ Vt) {
  const int K = 1024;
  __shared__ __align__(16) __hip_bfloat16 As[128 * 32];
  __shared__ __align__(16) __hip_bfloat16 Bs[128 * 32];
  const int t = threadIdx.x;
  const int lane = t & 63, wv = t >> 6;
  const int wm = (wv >> 1) * 64, wn = (wv & 1) * 64;
  const int lr = lane & 15, lq = lane >> 4;
  const int m0 = blockIdx.y * 128, n0 = blockIdx.x * 128;

  f32x4 acc[4][4] = {};

  const int arow = t >> 2;
  const int acol = (t & 3) * 8;
  const __hip_bfloat16* Ag = A + (long)(m0 + arow) * K + acol;
  const __hip_bfloat16* Bg = B + (long)(n0 + arow) * K + acol;
  __hip_bfloat16* Asl = As + t * 8;
  __hip_bfloat16* Bsl = Bs + t * 8;

  for (int kk = 0; kk < K; kk += 32) {
    gload16(Ag + kk, Asl);
    gload16(Ag + kk + 64 * K, Asl + 2048);
    gload16(Bg + kk, Bsl);
    gload16(Bg + kk + 64 * K, Bsl + 2048);
    __syncthreads();
    bf16x8 af[4], bf[4];
#pragma unroll
    for (int i = 0; i < 4; ++i)
      af[i] = *(const bf16x8*)&As[(wm + i * 16 + lr) * 32 + lq * 8];
#pragma unroll
    for (int j = 0; j < 4; ++j)
      bf[j] = *(const bf16x8*)&Bs[(wn + j * 16 + lr) * 32 + lq * 8];
#pragma unroll
    for (int i = 0; i < 4; ++i)
#pragma unroll
      for (int j = 0; j < 4; ++j)
        acc[i][j] = MFMA16(af[i], bf[j], acc[i][j]);
    __syncthreads();
  }

#pragma unroll
  for (int i = 0; i < 4; ++i) {
#pragma unroll
    for (int j = 0; j < 4; ++j) {
      int col = n0 + wn + j * 16 + lr;
      int tsel = col >> 10, rem = col & 1023;
      int h = rem >> 6, d = rem & 63;
      float bs = bias[col];
      int rowb = m0 + wm + i * 16 + lq * 4;
#pragma unroll
      for (int r = 0; r < 4; ++r) {
        int m = rowb + r;
        int b = m >> 11, sdx = m & 2047;
        __hip_bfloat16 v = __float2bfloat16(acc[i][j][r] + bs);
        long bh = (long)(b * 16 + h);
        if (tsel == 0)       Qo[(bh * 2048 + sdx) * 64 + d] = v;
        else if (tsel == 1)  Ko[(bh * 2048 + sdx) * 64 + d] = v;
        else                 Vt[(bh * 64 + d) * 2048 + sdx] = v;
      }
    }
  }
}

// ---------------- fused attention v6: lane-local P + QBLK=32 + K/V dbuf ----------------
// r5 diagnosis: LDS-pipe bound (~2900 pipe-cyc / 16k-iter; doubling occupancy
// changed nothing). v6 removes LDS work per output:
//  (1) S^T output layout (lane: k=lq*4+r, q=lr) IS the 16x16x16 MFMA operand
//      layout -> P never touches LDS. PV: ctx^T += mfma16x16(V^T b64 frag, p4).
//  (2) QBLK=32: staging DMA (the largest term) halves per unit work; K frags
//      shared across the two q-tiles.
//  (3) Full K/V double-buffer (128 KB) + 16 KB psum -> 1 block/CU (TLP proved
//      useless in r5); 3 barriers/iter; stages issued at iter top get a full
//      iteration to land; vmcnt(0) only at the switch barrier.
// Softmax over heads: per-wave 2-head partials -> psum; waves 0/1 reduce the
// two q-tiles in parallel, publish rcp; all waves read inv once.
// VGPR peak ~130 (ctx 64 + qf 32 + s 16 + transients); launch_bounds(512,2)
// lifts the cap so nothing spills.
__global__ __launch_bounds__(512, 2) void attn_kernel(
    const __hip_bfloat16* __restrict__ Q,
    const __hip_bfloat16* __restrict__ K,
    const __hip_bfloat16* __restrict__ Vt,
    __hip_bfloat16* __restrict__ part) {
  __shared__ __align__(16) __hip_bfloat16 KsA[16 * 16 * 64];  // 32 KB
  __shared__ __align__(16) __hip_bfloat16 KsB[16 * 16 * 64];  // 32 KB
  __shared__ __align__(16) __hip_bfloat16 VsA[16 * 64 * 16];  // 32 KB [h][64d][16k]
  __shared__ __align__(16) __hip_bfloat16 VsB[16 * 64 * 16];  // 32 KB
  __shared__ __align__(16) float psum[2 * 8 * 16 * 16];       // 16 KB [qt][w][q][k]

  const int t = threadIdx.x, lane = t & 63, wv = t >> 6;
  const int lr = lane & 15, lq = lane >> 4;
  const int h0 = wv * 2;  // this wave's two heads
  const int combo = blockIdx.x & 7;
  const int b = combo & 1, chunk = combo >> 1;
  const int q0 = (blockIdx.x >> 3) * 32;
  const int k0 = chunk * 512;
  const float c = 0.03125f * 1.44269504f;  // (1/sqrt(E)) * log2(e), E=1024
  const long bh16 = (long)(b * 16);

  // K staging: row rho = h*16+kl (128B), 8 granules; LDS linear, swizzle on SOURCE.
  auto stageK = [&](__hip_bfloat16* dst, int kks) {
#pragma unroll
    for (int cc = 0; cc < 4; ++cc) {
      const int p = cc * 8192 + t * 16;
      const int rho = p >> 7;
      const int hh = rho >> 4, kl = rho & 15;
      const int g = ((p >> 4) & 7) ^ (rho & 7);
      const __hip_bfloat16* src = K + ((bh16 + hh) * 2048 + kks + kl) * 64 + g * 8;
      gload16(src, (char*)dst + p);
    }
    fence_order();
  };
  // V staging: row rho = h*64+d (32B, 2 granules), linear both sides.
  auto stageV = [&](__hip_bfloat16* dst, int kks) {
#pragma unroll
    for (int cc = 0; cc < 4; ++cc) {
      const int p = cc * 8192 + t * 16;
      const int rho = p >> 5;
      const int hh = rho >> 6, d = rho & 63;
      const int g = (p >> 4) & 1;
      const __hip_bfloat16* src = Vt + ((bh16 + hh) * 64 + d) * 2048 + kks + g * 8;
      gload16(src, (char*)dst + p);
    }
    fence_order();
  };

  // Q fragments (B-operand of S^T): lane holds Q[q0+qt*16+lr][dh*32+lq*8..+8]
  bf16x8 qf[2][2][2];  // [hh][qt][dh]
#pragma unroll
  for (int hh = 0; hh < 2; ++hh)
#pragma unroll
    for (int qt = 0; qt < 2; ++qt)
#pragma unroll
      for (int dh = 0; dh < 2; ++dh)
        qf[hh][qt][dh] = *(const bf16x8*)(
            Q + ((bh16 + h0 + hh) * 2048 + q0 + qt * 16 + lr) * 64 + dh * 32 + lq * 8);

  stageK(KsA, k0);
  stageV(VsA, k0);
  asm volatile("s_waitcnt vmcnt(0)" ::: "memory");
  block_sync_lds();

  f32x4 ctx[2][2][4] = {};  // [hh][qt][dt], lane: d = dt*16+lq*4+r, q = qt*16+lr

  auto body = [&](const __hip_bfloat16* Kc, const __hip_bfloat16* Vc,
                  __hip_bfloat16* Kn, __hip_bfloat16* Vn, int kt) {
    // ---- issue next tiles first: full-iteration latency window ----
    if (kt < 31) {
      stageK(Kn, k0 + (kt + 1) * 16);
      stageV(Vn, k0 + (kt + 1) * 16);
    }
    // ---- S^T = K·Q^T: 2 heads x 2 q-tiles, K frags shared across qt ----
    f32x4 s[2][2];
    __builtin_amdgcn_s_setprio(1);
#pragma unroll
    for (int hh = 0; hh < 2; ++hh) {
      const int rho = (h0 + hh) * 16 + lr;
      const __hip_bfloat16* kr = Kc + rho * 64;
      bf16x8 kf0 = *(const bf16x8*)(kr + ((lq ^ (rho & 7)) << 3));
      bf16x8 kf1 = *(const bf16x8*)(kr + (((lq + 4) ^ (rho & 7)) << 3));
#pragma unroll
      for (int qt = 0; qt < 2; ++qt) {
        f32x4 a = {};
        a = MFMA16(kf0, qf[hh][qt][0], a);
        a = MFMA16(kf1, qf[hh][qt][1], a);
        s[hh][qt] = a;
      }
    }
    __builtin_amdgcn_s_setprio(0);
    // ---- exp + per-wave 2-head partial sums ----
#pragma unroll
    for (int qt = 0; qt < 2; ++qt) {
      f32x4 pp;
#pragma unroll
      for (int r = 0; r < 4; ++r) {
        s[0][qt][r] = __builtin_amdgcn_exp2f(s[0][qt][r] * c);
        s[1][qt][r] = __builtin_amdgcn_exp2f(s[1][qt][r] * c);
        pp[r] = s[0][qt][r] + s[1][qt][r];
      }
      *(f32x4*)&psum[qt * 2048 + wv * 256 + lr * 16 + lq * 4] = pp;
    }
    block_sync_lds();  // BAR1: partials visible
    // ---- waves 0/1 reduce q-tiles 0/1 in parallel; publish rcp ----
    if (wv < 2) {
      f32x4 tot = {};
#pragma unroll
      for (int w2 = 0; w2 < 8; ++w2)
        tot += *(const f32x4*)&psum[wv * 2048 + w2 * 256 + lr * 16 + lq * 4];
      f32x4 inv;
#pragma unroll
      for (int r = 0; r < 4; ++r) inv[r] = __builtin_amdgcn_rcpf(tot[r]);
      *(f32x4*)&psum[wv * 2048 + lr * 16 + lq * 4] = inv;
    }
    block_sync_lds();  // BAR2: inv visible (V(kt) landed since prev iter's drain)
    // ---- PV: p4 stays in registers; V read as b64 frags, shared across qt ----
    __builtin_amdgcn_s_setprio(1);
    f32x4 inv0 = *(const f32x4*)&psum[lr * 16 + lq * 4];
    f32x4 inv1 = *(const f32x4*)&psum[2048 + lr * 16 + lq * 4];
#pragma unroll
    for (int hh = 0; hh < 2; ++hh) {
      const char* vb = (const char*)Vc + (h0 + hh) * 2048;
      bf16x4 vf[4];
#pragma unroll
      for (int dt = 0; dt < 4; ++dt)
        vf[dt] = *(const bf16x4*)(vb + (dt * 16 + lr) * 32 + lq * 8);
#pragma unroll
      for (int qt = 0; qt < 2; ++qt) {
        const f32x4 iv = qt ? inv1 : inv0;
        bf16x4 p4;
#pragma unroll
        for (int r = 0; r < 4; ++r) p4[r] = (short)bf16bits(s[hh][qt][r] * iv[r]);
#pragma unroll
        for (int dt = 0; dt < 4; ++dt)
          ctx[hh][qt][dt] = MFMA16K16(vf[dt], p4, ctx[hh][qt][dt]);
      }
    }
    __builtin_amdgcn_s_setprio(0);
    asm volatile("s_waitcnt vmcnt(0)" ::: "memory");  // next K/V landed
    block_sync_lds();  // BAR3: buffer switch
  };

#pragma unroll 1
  for (int kp = 0; kp < 16; ++kp) {
    body(KsA, VsA, KsB, VsB, 2 * kp);
    body(KsB, VsB, KsA, VsA, 2 * kp + 1);
  }

  // ---- epilogue: per q-tile, ctx^T -> LDS (reuse KsA) -> coalesced store ----
  unsigned short* Pc = (unsigned short*)KsA;
#pragma unroll
  for (int qt = 0; qt < 2; ++qt) {
    if (qt) block_sync_lds();  // pass-0 reads done before overwrite
#pragma unroll
    for (int hh = 0; hh < 2; ++hh) {
      const int h = h0 + hh;
#pragma unroll
      for (int dt = 0; dt < 4; ++dt) {
        bf16x4 pk;
#pragma unroll
        for (int r = 0; r < 4; ++r) pk[r] = (short)bf16bits(ctx[hh][qt][dt][r]);
        const int o = h * 128 + dt * 32 + lq * 8;  // byte off in hd-row (d=dt*16+lq*4+r)
        *(bf16x4*)((char*)Pc + lr * 2048 + (o ^ ((lr & 7) << 4))) = pk;
      }
    }
    block_sync_lds();
    unsigned short* gbase = (unsigned short*)part +
        ((long)(chunk * 4096 + b * 2048 + q0 + qt * 16)) * 1024;
#pragma unroll
    for (int j = 0; j < 4; ++j) {
      int gf = (j * 512 + t) * 8;  // flat over [16q][16h*64d]
      int q = gf >> 10, hd = gf & 1023;
      u16x8 v = *(const u16x8*)((char*)Pc + q * 2048 + ((hd * 2) ^ ((q & 7) << 4)));
      *(u16x8*)&gbase[gf] = v;
    }
  }
}

// ---------------- reduce 4 bf16 chunk partials + cast to bf16 ----------------
__global__ void reduce_cast_kernel(const unsigned short* __restrict__ part,
                                   __hip_bfloat16* __restrict__ dst) {
  int i = blockIdx.x * blockDim.x + threadIdx.x;  // 1M threads, 4 elems each
  const long S4 = (long)4096 * 1024 / 4;          // ushort4 units per chunk
  const ushort4* p = (const ushort4*)part;
  float sx = 0.f, sy = 0.f, sz = 0.f, sw = 0.f;
#pragma unroll
  for (int c = 0; c < 4; ++c) {
    ushort4 v = p[i + c * S4];
    sx += bf2f(v.x); sy += bf2f(v.y); sz += bf2f(v.z); sw += bf2f(v.w);
  }
  ushort4 u;
  u.x = bf16bits(sx); u.y = bf16bits(sy); u.z = bf16bits(sz); u.w = bf16bits(sw);
  ((ushort4*)dst)[i] = u;
}

// ---------------- GEMM2: out = ctxb @ woutb^T + b_out (fp32 out) ----------------
__global__ __launch_bounds__(256) void gemm_out_kernel(
    const __hip_bfloat16* __restrict__ A,   // [4096][1024]
    const __hip_bfloat16* __restrict__ B,   // [1024][1024]
    const float* __restrict__ bias,
    float* __restrict__ out) {
  const int K = 1024;
  __shared__ __align__(16) __hip_bfloat16 As[128 * 32];
  __shared__ __align__(16) __hip_bfloat16 Bs[128 * 32];
  const int t = threadIdx.x;
  const int lane = t & 63, wv = t >> 6;
  const int wm = (wv >> 1) * 64, wn = (wv & 1) * 64;
  const int lr = lane & 15, lq = lane >> 4;
  const int m0 = blockIdx.y * 128, n0 = blockIdx.x * 128;

  f32x4 acc[4][4] = {};

  const int arow = t >> 2;
  const int acol = (t & 3) * 8;
  const __hip_bfloat16* Ag = A + (long)(m0 + arow) * K + acol;
  const __hip_bfloat16* Bg = B + (long)(n0 + arow) * K + acol;
  __hip_bfloat16* Asl = As + t * 8;
  __hip_bfloat16* Bsl = Bs + t * 8;

  for (int kk = 0; kk < K; kk += 32) {
    gload16(Ag + kk, Asl);
    gload16(Ag + kk + 64 * K, Asl + 2048);
    gload16(Bg + kk, Bsl);
    gload16(Bg + kk + 64 * K, Bsl + 2048);
    __syncthreads();
    bf16x8 af[4], bf[4];
#pragma unroll
    for (int i = 0; i < 4; ++i)
      af[i] = *(const bf16x8*)&As[(wm + i * 16 + lr) * 32 + lq * 8];
#pragma unroll
    for (int j = 0; j < 4; ++j)
      bf[j] = *(const bf16x8*)&Bs[(wn + j * 16 + lr) * 32 + lq * 8];
#pragma unroll
    for (int i = 0; i < 4; ++i)
#pragma unroll
      for (int j = 0; j < 4; ++j)
        acc[i][j] = MFMA16(af[i], bf[j], acc[i][j]);
    __syncthreads();
  }

#pragma unroll
  for (int i = 0; i < 4; ++i) {
#pragma unroll
    for (int j = 0; j < 4; ++j) {
      int col = n0 + wn + j * 16 + lr;
      float bs = bias[col];
      int rowb = m0 + wm + i * 16 + lq * 4;
#pragma unroll
      for (int r = 0; r < 4; ++r) {
        out[(long)(rowb + r) * 1024 + col] = acc[i][j][r] + bs;
      }
    }
  }
}

extern "C" void kernel_launch(void* const* d_in, const int* in_sizes, int n_in,
                              void* d_out, int out_size, void* d_ws, size_t ws_size,
                              hipStream_t stream) {
  const float* x     = (const float*)d_in[0];
  const float* w_qkv = (const float*)d_in[1];
  const float* b_qkv = (const float*)d_in[2];
  const float* w_out = (const float*)d_in[3];
  const float* b_out = (const float*)d_in[4];
  float* out = (float*)d_out;
  char* ws = (char*)d_ws;

  // workspace layout (80 MB total)
  __hip_bfloat16* xb    = (__hip_bfloat16*)(ws);                       // 8 MB
  __hip_bfloat16* wqkvb = (__hip_bfloat16*)(ws + (8ul << 20));         // 6 MB
  __hip_bfloat16* woutb = (__hip_bfloat16*)(ws + (14ul << 20));        // 2 MB
  __hip_bfloat16* Qb    = (__hip_bfloat16*)(ws + (16ul << 20));        // 8 MB
  __hip_bfloat16* Kb    = (__hip_bfloat16*)(ws + (24ul << 20));        // 8 MB
  __hip_bfloat16* Vtb   = (__hip_bfloat16*)(ws + (32ul << 20));        // 8 MB
  __hip_bfloat16* partb = (__hip_bfloat16*)(ws + (40ul << 20));        // 32 MB (4 bf16 chunks)
  __hip_bfloat16* ctxb  = (__hip_bfloat16*)(ws + (72ul << 20));        // 8 MB

  cast_kernel<<<4096, 256, 0, stream>>>(x, xb, 4194304 / 4);
  cast_kernel<<<3072, 256, 0, stream>>>(w_qkv, wqkvb, 3145728 / 4);
  cast_kernel<<<1024, 256, 0, stream>>>(w_out, woutb, 1048576 / 4);
  gemm_qkv_kernel<<<dim3(24, 32), 256, 0, stream>>>(xb, wqkvb, b_qkv, Qb, Kb, Vtb);
  attn_kernel<<<512, 512, 0, stream>>>(Qb, Kb, Vtb, partb);
  reduce_cast_kernel<<<4096, 256, 0, stream>>>((const unsigned short*)partb, ctxb);
  gemm_out_kernel<<<dim3(8, 32), 256, 0, stream>>>(ctxb, woutb, b_out, out);
}

// Round 7
// 304.568 us; speedup vs baseline: 1.8917x; 1.0534x over previous
//
#include <hip/hip_runtime.h>
#include <hip/hip_bf16.h>
#include <stdint.h>

typedef float  f32x4  __attribute__((ext_vector_type(4)));
typedef short  bf16x8 __attribute__((ext_vector_type(8)));
typedef short  bf16x4 __attribute__((ext_vector_type(4)));
typedef unsigned short u16x8 __attribute__((ext_vector_type(8)));

#define MFMA16(a, b, c) __builtin_amdgcn_mfma_f32_16x16x32_bf16((a), (b), (c), 0, 0, 0)

// 16x16x16 bf16 MFMA: A/B = 4 bf16/lane (k = (lane>>4)*4 + reg), C/D standard 16x16.
#if __has_builtin(__builtin_amdgcn_mfma_f32_16x16x16bf16_1k)
#define MFMA16K16(a, b, c) __builtin_amdgcn_mfma_f32_16x16x16bf16_1k((a), (b), (c), 0, 0, 0)
#else
__device__ __forceinline__ f32x4 mfma16k16_asm(bf16x4 a, bf16x4 b, f32x4 c) {
  f32x4 d;
  asm volatile("v_mfma_f32_16x16x16_bf16 %0, %1, %2, %3"
               : "=v"(d) : "v"(a), "v"(b), "v"(c));
  return d;
}
#define MFMA16K16(a, b, c) mfma16k16_asm((a), (b), (c))
#endif

__device__ __forceinline__ void gload16(const void* g, void* l) {
  __builtin_amdgcn_global_load_lds((const __attribute__((address_space(1))) void*)g,
                                   (__attribute__((address_space(3))) void*)l,
                                   16, 0, 0);
}

__device__ __forceinline__ unsigned short bf16bits(float f) {
  __hip_bfloat16 h = __float2bfloat16(f);
  return *(unsigned short*)&h;
}

__device__ __forceinline__ float bf2f(unsigned short u) {
  unsigned int x = ((unsigned int)u) << 16;
  return *(float*)&x;
}

// LDS-only barrier: drains DS ops, leaves LDS-DMA (vmcnt) in flight.
__device__ __forceinline__ void block_sync_lds() {
  asm volatile("s_waitcnt lgkmcnt(0)" ::: "memory");
  __builtin_amdgcn_s_barrier();
  asm volatile("" ::: "memory");
}

__device__ __forceinline__ void fence_order() { asm volatile("" ::: "memory"); }

// ---------------- fp32 -> bf16 cast, 4 elems/thread ----------------
__global__ void cast_kernel(const float* __restrict__ s, __hip_bfloat16* __restrict__ d, int n4) {
  int i = blockIdx.x * blockDim.x + threadIdx.x;
  if (i < n4) {
    float4 v = ((const float4*)s)[i];
    ushort4 u;
    u.x = bf16bits(v.x); u.y = bf16bits(v.y); u.z = bf16bits(v.z); u.w = bf16bits(v.w);
    ((ushort4*)d)[i] = u;
  }
}

// ---------------- GEMM1: qkv = xb @ wqkvb^T + b_qkv; scatter to Q,K,Vt (bf16) ----------------
__global__ __launch_bounds__(256) void gemm_qkv_kernel(
    const __hip_bfloat16* __restrict__ A,
    const __hip_bfloat16* __restrict__ B,
    const float* __restrict__ bias,
    __hip_bfloat16* __restrict__ Qo,
    __hip_bfloat16* __restrict__ Ko,
    __hip_bfloat16* __restrict__ Vt) {
  const int K = 1024;
  __shared__ __align__(16) __hip_bfloat16 As[128 * 32];
  __shared__ __align__(16) __hip_bfloat16 Bs[128 * 32];
  const int t = threadIdx.x;
  const int lane = t & 63, wv = t >> 6;
  const int wm = (wv >> 1) * 64, wn = (wv & 1) * 64;
  const int lr = lane & 15, lq = lane >> 4;
  const int m0 = blockIdx.y * 128, n0 = blockIdx.x * 128;

  f32x4 acc[4][4] = {};

  const int arow = t >> 2;
  const int acol = (t & 3) * 8;
  const __hip_bfloat16* Ag = A + (long)(m0 + arow) * K + acol;
  const __hip_bfloat16* Bg = B + (long)(n0 + arow) * K + acol;
  __hip_bfloat16* Asl = As + t * 8;
  __hip_bfloat16* Bsl = Bs + t * 8;

  for (int kk = 0; kk < K; kk += 32) {
    gload16(Ag + kk, Asl);
    gload16(Ag + kk + 64 * K, Asl + 2048);
    gload16(Bg + kk, Bsl);
    gload16(Bg + kk + 64 * K, Bsl + 2048);
    __syncthreads();
    bf16x8 af[4], bf[4];
#pragma unroll
    for (int i = 0; i < 4; ++i)
      af[i] = *(const bf16x8*)&As[(wm + i * 16 + lr) * 32 + lq * 8];
#pragma unroll
    for (int j = 0; j < 4; ++j)
      bf[j] = *(const bf16x8*)&Bs[(wn + j * 16 + lr) * 32 + lq * 8];
#pragma unroll
    for (int i = 0; i < 4; ++i)
#pragma unroll
      for (int j = 0; j < 4; ++j)
        acc[i][j] = MFMA16(af[i], bf[j], acc[i][j]);
    __syncthreads();
  }

#pragma unroll
  for (int i = 0; i < 4; ++i) {
#pragma unroll
    for (int j = 0; j < 4; ++j) {
      int col = n0 + wn + j * 16 + lr;
      int tsel = col >> 10, rem = col & 1023;
      int h = rem >> 6, d = rem & 63;
      float bs = bias[col];
      int rowb = m0 + wm + i * 16 + lq * 4;
#pragma unroll
      for (int r = 0; r < 4; ++r) {
        int m = rowb + r;
        int b = m >> 11, sdx = m & 2047;
        __hip_bfloat16 v = __float2bfloat16(acc[i][j][r] + bs);
        long bh = (long)(b * 16 + h);
        if (tsel == 0)       Qo[(bh * 2048 + sdx) * 64 + d] = v;
        else if (tsel == 1)  Ko[(bh * 2048 + sdx) * 64 + d] = v;
        else                 Vt[(bh * 64 + d) * 2048 + sdx] = v;
      }
    }
  }
}

// ---------------- fused attention v7: v6 + bank-conflict fixes + V-load hoist ----------------
// r6 diagnosis: 22M bank conflicts (~1340 cy/iter/CU): psum [q][16k] rows are
// 8-way conflicted; V b64 reads 4-way; V-frag loads sat after BAR2 in the
// critical chain. v7 (no structural change, VGPR stays ~110):
//  (1) psum padded to 20-float rows (16B-aligned) -> <=2-way everywhere.
//  (2) V 16B-half XOR swizzle keyed on (row>>2)&1, applied BOTH on DMA source
//      and read offset (involution) -> 4-way -> 2-way.
//  (3) V-frag loads hoisted before BAR1 (buffer landed at prev iter's drain;
//      dbuf -> no WAR hazard): overlap with exp/psum/reduce.
__global__ __launch_bounds__(512, 2) void attn_kernel(
    const __hip_bfloat16* __restrict__ Q,
    const __hip_bfloat16* __restrict__ K,
    const __hip_bfloat16* __restrict__ Vt,
    __hip_bfloat16* __restrict__ part) {
  __shared__ __align__(16) __hip_bfloat16 KsA[16 * 16 * 64];  // 32 KB
  __shared__ __align__(16) __hip_bfloat16 KsB[16 * 16 * 64];  // 32 KB
  __shared__ __align__(16) __hip_bfloat16 VsA[16 * 64 * 16];  // 32 KB [h][64d][16k], half-swz
  __shared__ __align__(16) __hip_bfloat16 VsB[16 * 64 * 16];  // 32 KB
  __shared__ __align__(16) float psum[2 * 8 * 320];           // 20 KB [qt][w][q][20pad]

  const int t = threadIdx.x, lane = t & 63, wv = t >> 6;
  const int lr = lane & 15, lq = lane >> 4;
  const int h0 = wv * 2;  // this wave's two heads
  const int combo = blockIdx.x & 7;
  const int b = combo & 1, chunk = combo >> 1;
  const int q0 = (blockIdx.x >> 3) * 32;
  const int k0 = chunk * 512;
  const float c = 0.03125f * 1.44269504f;  // (1/sqrt(E)) * log2(e), E=1024
  const long bh16 = (long)(b * 16);

  // K staging: row rho = h*16+kl (128B), 8 granules; LDS linear, swizzle on SOURCE.
  auto stageK = [&](__hip_bfloat16* dst, int kks) {
#pragma unroll
    for (int cc = 0; cc < 4; ++cc) {
      const int p = cc * 8192 + t * 16;
      const int rho = p >> 7;
      const int hh = rho >> 4, kl = rho & 15;
      const int g = ((p >> 4) & 7) ^ (rho & 7);
      const __hip_bfloat16* src = K + ((bh16 + hh) * 2048 + kks + kl) * 64 + g * 8;
      gload16(src, (char*)dst + p);
    }
    fence_order();
  };
  // V staging: row rho = h*64+d (32B, 2 granules); half-swizzle g ^= (rho>>2)&1 on SOURCE.
  auto stageV = [&](__hip_bfloat16* dst, int kks) {
#pragma unroll
    for (int cc = 0; cc < 4; ++cc) {
      const int p = cc * 8192 + t * 16;
      const int rho = p >> 5;
      const int hh = rho >> 6, d = rho & 63;
      const int g = ((p >> 4) & 1) ^ ((rho >> 2) & 1);
      const __hip_bfloat16* src = Vt + ((bh16 + hh) * 64 + d) * 2048 + kks + g * 8;
      gload16(src, (char*)dst + p);
    }
    fence_order();
  };

  // Q fragments (B-operand of S^T): lane holds Q[q0+qt*16+lr][dh*32+lq*8..+8]
  bf16x8 qf[2][2][2];  // [hh][qt][dh]
#pragma unroll
  for (int hh = 0; hh < 2; ++hh)
#pragma unroll
    for (int qt = 0; qt < 2; ++qt)
#pragma unroll
      for (int dh = 0; dh < 2; ++dh)
        qf[hh][qt][dh] = *(const bf16x8*)(
            Q + ((bh16 + h0 + hh) * 2048 + q0 + qt * 16 + lr) * 64 + dh * 32 + lq * 8);

  stageK(KsA, k0);
  stageV(VsA, k0);
  asm volatile("s_waitcnt vmcnt(0)" ::: "memory");
  block_sync_lds();

  f32x4 ctx[2][2][4] = {};  // [hh][qt][dt], lane: d = dt*16+lq*4+r, q = qt*16+lr

  auto body = [&](const __hip_bfloat16* Kc, const __hip_bfloat16* Vc,
                  __hip_bfloat16* Kn, __hip_bfloat16* Vn, int kt) {
    // ---- issue next tiles first: full-iteration latency window ----
    if (kt < 31) {
      stageK(Kn, k0 + (kt + 1) * 16);
      stageV(Vn, k0 + (kt + 1) * 16);
    }
    // ---- S^T = K·Q^T: 2 heads x 2 q-tiles, K frags shared across qt ----
    f32x4 s[2][2];
    __builtin_amdgcn_s_setprio(1);
#pragma unroll
    for (int hh = 0; hh < 2; ++hh) {
      const int rho = (h0 + hh) * 16 + lr;
      const __hip_bfloat16* kr = Kc + rho * 64;
      bf16x8 kf0 = *(const bf16x8*)(kr + ((lq ^ (rho & 7)) << 3));
      bf16x8 kf1 = *(const bf16x8*)(kr + (((lq + 4) ^ (rho & 7)) << 3));
#pragma unroll
      for (int qt = 0; qt < 2; ++qt) {
        f32x4 a = {};
        a = MFMA16(kf0, qf[hh][qt][0], a);
        a = MFMA16(kf1, qf[hh][qt][1], a);
        s[hh][qt] = a;
      }
    }
    __builtin_amdgcn_s_setprio(0);
    // ---- exp + per-wave 2-head partial sums (padded psum rows) ----
#pragma unroll
    for (int qt = 0; qt < 2; ++qt) {
      f32x4 pp;
#pragma unroll
      for (int r = 0; r < 4; ++r) {
        s[0][qt][r] = __builtin_amdgcn_exp2f(s[0][qt][r] * c);
        s[1][qt][r] = __builtin_amdgcn_exp2f(s[1][qt][r] * c);
        pp[r] = s[0][qt][r] + s[1][qt][r];
      }
      *(f32x4*)&psum[qt * 2560 + wv * 320 + lr * 20 + lq * 4] = pp;
    }
    // ---- V-frag loads hoisted here: V(kt) landed at prev iter's drain; dbuf
    //      means stageV above writes the OTHER buffer (no WAR). Overlaps with
    //      the barrier wait + wave0/1 reduce. Half-swizzled offset (2-way max).
    bf16x4 vf[2][4];
#pragma unroll
    for (int hh = 0; hh < 2; ++hh) {
      const char* vb = (const char*)Vc + (h0 + hh) * 2048;
#pragma unroll
      for (int dt = 0; dt < 4; ++dt)
        vf[hh][dt] = *(const bf16x4*)(
            vb + (dt * 16 + lr) * 32 + ((lq * 8) ^ (((lr >> 2) & 1) * 16)));
    }
    block_sync_lds();  // BAR1: partials visible
    // ---- waves 0/1 reduce q-tiles 0/1 in parallel; publish rcp ----
    if (wv < 2) {
      f32x4 tot = {};
#pragma unroll
      for (int w2 = 0; w2 < 8; ++w2)
        tot += *(const f32x4*)&psum[wv * 2560 + w2 * 320 + lr * 20 + lq * 4];
      f32x4 inv;
#pragma unroll
      for (int r = 0; r < 4; ++r) inv[r] = __builtin_amdgcn_rcpf(tot[r]);
      *(f32x4*)&psum[wv * 2560 + lr * 20 + lq * 4] = inv;  // w=0 slot, already consumed
    }
    block_sync_lds();  // BAR2: inv visible
    // ---- PV: p4 in registers; vf pre-loaded ----
    __builtin_amdgcn_s_setprio(1);
    f32x4 inv0 = *(const f32x4*)&psum[lr * 20 + lq * 4];
    f32x4 inv1 = *(const f32x4*)&psum[2560 + lr * 20 + lq * 4];
#pragma unroll
    for (int hh = 0; hh < 2; ++hh) {
#pragma unroll
      for (int qt = 0; qt < 2; ++qt) {
        const f32x4 iv = qt ? inv1 : inv0;
        bf16x4 p4;
#pragma unroll
        for (int r = 0; r < 4; ++r) p4[r] = (short)bf16bits(s[hh][qt][r] * iv[r]);
#pragma unroll
        for (int dt = 0; dt < 4; ++dt)
          ctx[hh][qt][dt] = MFMA16K16(vf[hh][dt], p4, ctx[hh][qt][dt]);
      }
    }
    __builtin_amdgcn_s_setprio(0);
    asm volatile("s_waitcnt vmcnt(0)" ::: "memory");  // next K/V landed
    block_sync_lds();  // BAR3: buffer switch
  };

#pragma unroll 1
  for (int kp = 0; kp < 16; ++kp) {
    body(KsA, VsA, KsB, VsB, 2 * kp);
    body(KsB, VsB, KsA, VsA, 2 * kp + 1);
  }

  // ---- epilogue: per q-tile, ctx^T -> LDS (reuse KsA) -> coalesced store ----
  unsigned short* Pc = (unsigned short*)KsA;
#pragma unroll
  for (int qt = 0; qt < 2; ++qt) {
    if (qt) block_sync_lds();  // pass-0 reads done before overwrite
#pragma unroll
    for (int hh = 0; hh < 2; ++hh) {
      const int h = h0 + hh;
#pragma unroll
      for (int dt = 0; dt < 4; ++dt) {
        bf16x4 pk;
#pragma unroll
        for (int r = 0; r < 4; ++r) pk[r] = (short)bf16bits(ctx[hh][qt][dt][r]);
        const int o = h * 128 + dt * 32 + lq * 8;  // byte off in hd-row (d=dt*16+lq*4+r)
        *(bf16x4*)((char*)Pc + lr * 2048 + (o ^ ((lr & 7) << 4))) = pk;
      }
    }
    block_sync_lds();
    unsigned short* gbase = (unsigned short*)part +
        ((long)(chunk * 4096 + b * 2048 + q0 + qt * 16)) * 1024;
#pragma unroll
    for (int j = 0; j < 4; ++j) {
      int gf = (j * 512 + t) * 8;  // flat over [16q][16h*64d]
      int q = gf >> 10, hd = gf & 1023;
      u16x8 v = *(const u16x8*)((char*)Pc + q * 2048 + ((hd * 2) ^ ((q & 7) << 4)));
      *(u16x8*)&gbase[gf] = v;
    }
  }
}

// ---------------- reduce 4 bf16 chunk partials + cast to bf16 ----------------
__global__ void reduce_cast_kernel(const unsigned short* __restrict__ part,
                                   __hip_bfloat16* __restrict__ dst) {
  int i = blockIdx.x * blockDim.x + threadIdx.x;  // 1M threads, 4 elems each
  const long S4 = (long)4096 * 1024 / 4;          // ushort4 units per chunk
  const ushort4* p = (const ushort4*)part;
  float sx = 0.f, sy = 0.f, sz = 0.f, sw = 0.f;
#pragma unroll
  for (int c = 0; c < 4; ++c) {
    ushort4 v = p[i + c * S4];
    sx += bf2f(v.x); sy += bf2f(v.y); sz += bf2f(v.z); sw += bf2f(v.w);
  }
  ushort4 u;
  u.x = bf16bits(sx); u.y = bf16bits(sy); u.z = bf16bits(sz); u.w = bf16bits(sw);
  ((ushort4*)dst)[i] = u;
}

// ---------------- GEMM2: out = ctxb @ woutb^T + b_out (fp32 out) ----------------
__global__ __launch_bounds__(256) void gemm_out_kernel(
    const __hip_bfloat16* __restrict__ A,   // [4096][1024]
    const __hip_bfloat16* __restrict__ B,   // [1024][1024]
    const float* __restrict__ bias,
    float* __restrict__ out) {
  const int K = 1024;
  __shared__ __align__(16) __hip_bfloat16 As[128 * 32];
  __shared__ __align__(16) __hip_bfloat16 Bs[128 * 32];
  const int t = threadIdx.x;
  const int lane = t & 63, wv = t >> 6;
  const int wm = (wv >> 1) * 64, wn = (wv & 1) * 64;
  const int lr = lane & 15, lq = lane >> 4;
  const int m0 = blockIdx.y * 128, n0 = blockIdx.x * 128;

  f32x4 acc[4][4] = {};

  const int arow = t >> 2;
  const int acol = (t & 3) * 8;
  const __hip_bfloat16* Ag = A + (long)(m0 + arow) * K + acol;
  const __hip_bfloat16* Bg = B + (long)(n0 + arow) * K + acol;
  __hip_bfloat16* Asl = As + t * 8;
  __hip_bfloat16* Bsl = Bs + t * 8;

  for (int kk = 0; kk < K; kk += 32) {
    gload16(Ag + kk, Asl);
    gload16(Ag + kk + 64 * K, Asl + 2048);
    gload16(Bg + kk, Bsl);
    gload16(Bg + kk + 64 * K, Bsl + 2048);
    __syncthreads();
    bf16x8 af[4], bf[4];
#pragma unroll
    for (int i = 0; i < 4; ++i)
      af[i] = *(const bf16x8*)&As[(wm + i * 16 + lr) * 32 + lq * 8];
#pragma unroll
    for (int j = 0; j < 4; ++j)
      bf[j] = *(const bf16x8*)&Bs[(wn + j * 16 + lr) * 32 + lq * 8];
#pragma unroll
    for (int i = 0; i < 4; ++i)
#pragma unroll
      for (int j = 0; j < 4; ++j)
        acc[i][j] = MFMA16(af[i], bf[j], acc[i][j]);
    __syncthreads();
  }

#pragma unroll
  for (int i = 0; i < 4; ++i) {
#pragma unroll
    for (int j = 0; j < 4; ++j) {
      int col = n0 + wn + j * 16 + lr;
      float bs = bias[col];
      int rowb = m0 + wm + i * 16 + lq * 4;
#pragma unroll
      for (int r = 0; r < 4; ++r) {
        out[(long)(rowb + r) * 1024 + col] = acc[i][j][r] + bs;
      }
    }
  }
}

extern "C" void kernel_launch(void* const* d_in, const int* in_sizes, int n_in,
                              void* d_out, int out_size, void* d_ws, size_t ws_size,
                              hipStream_t stream) {
  const float* x     = (const float*)d_in[0];
  const float* w_qkv = (const float*)d_in[1];
  const float* b_qkv = (const float*)d_in[2];
  const float* w_out = (const float*)d_in[3];
  const float* b_out = (const float*)d_in[4];
  float* out = (float*)d_out;
  char* ws = (char*)d_ws;

  // workspace layout (80 MB total)
  __hip_bfloat16* xb    = (__hip_bfloat16*)(ws);                       // 8 MB
  __hip_bfloat16* wqkvb = (__hip_bfloat16*)(ws + (8ul << 20));         // 6 MB
  __hip_bfloat16* woutb = (__hip_bfloat16*)(ws + (14ul << 20));        // 2 MB
  __hip_bfloat16* Qb    = (__hip_bfloat16*)(ws + (16ul << 20));        // 8 MB
  __hip_bfloat16* Kb    = (__hip_bfloat16*)(ws + (24ul << 20));        // 8 MB
  __hip_bfloat16* Vtb   = (__hip_bfloat16*)(ws + (32ul << 20));        // 8 MB
  __hip_bfloat16* partb = (__hip_bfloat16*)(ws + (40ul << 20));        // 32 MB (4 bf16 chunks)
  __hip_bfloat16* ctxb  = (__hip_bfloat16*)(ws + (72ul << 20));        // 8 MB

  cast_kernel<<<4096, 256, 0, stream>>>(x, xb, 4194304 / 4);
  cast_kernel<<<3072, 256, 0, stream>>>(w_qkv, wqkvb, 3145728 / 4);
  cast_kernel<<<1024, 256, 0, stream>>>(w_out, woutb, 1048576 / 4);
  gemm_qkv_kernel<<<dim3(24, 32), 256, 0, stream>>>(xb, wqkvb, b_qkv, Qb, Kb, Vtb);
  attn_kernel<<<512, 512, 0, stream>>>(Qb, Kb, Vtb, partb);
  reduce_cast_kernel<<<4096, 256, 0, stream>>>((const unsigned short*)partb, ctxb);
  gemm_out_kernel<<<dim3(8, 32), 256, 0, stream>>>(ctxb, woutb, b_out, out);
}